// Round 1
// baseline (489.509 us; speedup 1.0000x reference)
//
#include <hip/hip_runtime.h>
#include <hip/hip_bf16.h>

// Problem constants
#define B_  512
#define H_  256
#define TK_ 512
#define V_  50000
#define NOOV_ 64
#define VE_ (V_ + NOOV_)   // 50064
#define NCB_ 391           // ceil(50000/128)

typedef __bf16 bf16_t;
typedef __bf16 bf16x8 __attribute__((ext_vector_type(8)));
typedef float  f32x4  __attribute__((ext_vector_type(4)));

#define DEVI __device__ __forceinline__

DEVI float fast_rcp(float x) { return __builtin_amdgcn_rcpf(x); }
DEVI float fast_tanh(float x) {
    // tanh(x) = 1 - 2/(e^{2x}+1); safe for all x (inf -> 1, 0 -> -1)
    float e = __expf(2.f * x);
    return 1.f - 2.f * fast_rcp(e + 1.f);
}
DEVI float fast_sig(float x) { return fast_rcp(1.f + __expf(-x)); }

DEVI unsigned f2bf1(float f) {
    unsigned u = __float_as_uint(f);
    return (u + 0x7fffu + ((u >> 16) & 1u)) >> 16;   // RNE
}
DEVI unsigned f2bf2(float lo, float hi) { return f2bf1(lo) | (f2bf1(hi) << 16); }

// ---------------------------------------------------------------------------
// Generic C[M,N] = A[M,K] * B[N,K]^T + bias   (bf16 MFMA, f32 in/out)
// BM=BN=128, BK=64, 256 threads (4 waves, each 64x64 as 4x4 frags of 16x16x32)
// M must be multiple of 128 (grid.y = M/128); K multiple of 64; N guarded.
// ---------------------------------------------------------------------------
template <int RELU>
__global__ __launch_bounds__(256) void gemm_bt(const float* __restrict__ A,
                                               const float* __restrict__ Bm,
                                               const float* __restrict__ bias,
                                               float* __restrict__ C,
                                               int N, int K) {
    __shared__ unsigned short As[128][72];
    __shared__ unsigned short Bs[128][72];
    const int tid = threadIdx.x;
    const int m0 = blockIdx.y * 128;
    const int n0 = blockIdx.x * 128;
    const int lane = tid & 63;
    const int wid = tid >> 6;
    const int wm = wid >> 1, wn = wid & 1;

    f32x4 acc[4][4] = {};

    for (int k0 = 0; k0 < K; k0 += 64) {
#pragma unroll
        for (int i = 0; i < 8; ++i) {
            int idx = tid + i * 256;       // 2048 float4 slots
            int r = idx >> 4;              // row 0..127
            int c4 = idx & 15;             // float4 col
            float4 va = *reinterpret_cast<const float4*>(&A[(size_t)(m0 + r) * K + k0 + c4 * 4]);
            uint2 pa;
            pa.x = f2bf2(va.x, va.y);
            pa.y = f2bf2(va.z, va.w);
            *reinterpret_cast<uint2*>(&As[r][c4 * 4]) = pa;

            float4 vb = make_float4(0.f, 0.f, 0.f, 0.f);
            if (n0 + r < N)
                vb = *reinterpret_cast<const float4*>(&Bm[(size_t)(n0 + r) * K + k0 + c4 * 4]);
            uint2 pb;
            pb.x = f2bf2(vb.x, vb.y);
            pb.y = f2bf2(vb.z, vb.w);
            *reinterpret_cast<uint2*>(&Bs[r][c4 * 4]) = pb;
        }
        __syncthreads();
#pragma unroll
        for (int ks = 0; ks < 64; ks += 32) {
            bf16x8 af[4], bfv[4];
            int koff = ks + (lane >> 4) * 8;
            int rA = wm * 64 + (lane & 15);
            int rB = wn * 64 + (lane & 15);
#pragma unroll
            for (int mi = 0; mi < 4; ++mi)
                af[mi] = *reinterpret_cast<const bf16x8*>(&As[rA + mi * 16][koff]);
#pragma unroll
            for (int ni = 0; ni < 4; ++ni)
                bfv[ni] = *reinterpret_cast<const bf16x8*>(&Bs[rB + ni * 16][koff]);
#pragma unroll
            for (int mi = 0; mi < 4; ++mi)
#pragma unroll
                for (int ni = 0; ni < 4; ++ni)
                    acc[mi][ni] = __builtin_amdgcn_mfma_f32_16x16x32_bf16(af[mi], bfv[ni], acc[mi][ni], 0, 0, 0);
        }
        __syncthreads();
    }

#pragma unroll
    for (int mi = 0; mi < 4; ++mi)
#pragma unroll
        for (int ni = 0; ni < 4; ++ni) {
            int c = n0 + wn * 64 + ni * 16 + (lane & 15);
            if (c < N) {
                float bv = bias[c];
#pragma unroll
                for (int r = 0; r < 4; ++r) {
                    int rr = m0 + wm * 64 + mi * 16 + (lane >> 4) * 4 + r;
                    float v = acc[mi][ni][r] + bv;
                    if (RELU) v = fmaxf(v, 0.f);
                    C[(size_t)rr * N + c] = v;
                }
            }
        }
}

// ---------------------------------------------------------------------------
// Big GEMM: logits = out1[512,256] @ Wo2[50000,256]^T + bo2; writes exp(logit)
// into final_dist region; deterministic per-(colblock,wave) row partial sums.
// grid = (391, 4)
// ---------------------------------------------------------------------------
__global__ __launch_bounds__(256) void gemm_exp(const float* __restrict__ A,
                                                const float* __restrict__ Wo2,
                                                const float* __restrict__ bo2,
                                                float* __restrict__ outF,
                                                float* __restrict__ ps) {
    __shared__ unsigned short As[128][72];
    __shared__ unsigned short Bs[128][72];
    const int tid = threadIdx.x;
    const int cb = blockIdx.x;
    const int m0 = blockIdx.y * 128;
    const int n0 = cb * 128;
    const int lane = tid & 63;
    const int wid = tid >> 6;
    const int wm = wid >> 1, wn = wid & 1;
    const int K = 256;

    f32x4 acc[4][4] = {};

    for (int k0 = 0; k0 < K; k0 += 64) {
#pragma unroll
        for (int i = 0; i < 8; ++i) {
            int idx = tid + i * 256;
            int r = idx >> 4;
            int c4 = idx & 15;
            float4 va = *reinterpret_cast<const float4*>(&A[(size_t)(m0 + r) * K + k0 + c4 * 4]);
            uint2 pa;
            pa.x = f2bf2(va.x, va.y);
            pa.y = f2bf2(va.z, va.w);
            *reinterpret_cast<uint2*>(&As[r][c4 * 4]) = pa;

            float4 vb = make_float4(0.f, 0.f, 0.f, 0.f);
            if (n0 + r < V_)
                vb = *reinterpret_cast<const float4*>(&Wo2[(size_t)(n0 + r) * K + k0 + c4 * 4]);
            uint2 pb;
            pb.x = f2bf2(vb.x, vb.y);
            pb.y = f2bf2(vb.z, vb.w);
            *reinterpret_cast<uint2*>(&Bs[r][c4 * 4]) = pb;
        }
        __syncthreads();
#pragma unroll
        for (int ks = 0; ks < 64; ks += 32) {
            bf16x8 af[4], bfv[4];
            int koff = ks + (lane >> 4) * 8;
            int rA = wm * 64 + (lane & 15);
            int rB = wn * 64 + (lane & 15);
#pragma unroll
            for (int mi = 0; mi < 4; ++mi)
                af[mi] = *reinterpret_cast<const bf16x8*>(&As[rA + mi * 16][koff]);
#pragma unroll
            for (int ni = 0; ni < 4; ++ni)
                bfv[ni] = *reinterpret_cast<const bf16x8*>(&Bs[rB + ni * 16][koff]);
#pragma unroll
            for (int mi = 0; mi < 4; ++mi)
#pragma unroll
                for (int ni = 0; ni < 4; ++ni)
                    acc[mi][ni] = __builtin_amdgcn_mfma_f32_16x16x32_bf16(af[mi], bfv[ni], acc[mi][ni], 0, 0, 0);
        }
        __syncthreads();
    }

    float psum[4][4];
#pragma unroll
    for (int mi = 0; mi < 4; ++mi)
#pragma unroll
        for (int r = 0; r < 4; ++r) psum[mi][r] = 0.f;

#pragma unroll
    for (int mi = 0; mi < 4; ++mi)
#pragma unroll
        for (int ni = 0; ni < 4; ++ni) {
            int c = n0 + wn * 64 + ni * 16 + (lane & 15);
            bool ok = (c < V_);
            float bv = ok ? bo2[c] : 0.f;
#pragma unroll
            for (int r = 0; r < 4; ++r) {
                float p = 0.f;
                if (ok) {
                    int rr = m0 + wm * 64 + mi * 16 + (lane >> 4) * 4 + r;
                    p = __expf(acc[mi][ni][r] + bv);
                    outF[(size_t)rr * VE_ + c] = p;
                }
                psum[mi][r] += p;
            }
        }

    // reduce over the 16-lane column group, store per-(colblock, row, wave-n)
#pragma unroll
    for (int mi = 0; mi < 4; ++mi)
#pragma unroll
        for (int r = 0; r < 4; ++r) {
            float v = psum[mi][r];
            v += __shfl_xor(v, 1);
            v += __shfl_xor(v, 2);
            v += __shfl_xor(v, 4);
            v += __shfl_xor(v, 8);
            if ((lane & 15) == 0) {
                int rr = m0 + wm * 64 + mi * 16 + (lane >> 4) * 4 + r;
                ps[((size_t)cb * 512 + rr) * 2 + wn] = v;
            }
        }
}

// ---------------------------------------------------------------------------
// scores[b,t] = sum_d tanh(mem[t,d] + dec[b,d]) * vw[d]   (d=512)
// grid (TK/16, B/16), block 256: 16 t x 16 b per block, d chunks of 128
// ---------------------------------------------------------------------------
__global__ __launch_bounds__(256) void attn_scores(const float* __restrict__ mem,
                                                   const float* __restrict__ dec,
                                                   const float* __restrict__ vw,
                                                   float* __restrict__ scores) {
    __shared__ float ms[16][132];
    __shared__ float dsh[16][132];
    __shared__ float vs[128];
    const int tid = threadIdx.x;
    const int t0 = blockIdx.x * 16, b0 = blockIdx.y * 16;
    const int tl = tid & 15, bl = tid >> 4;
    float acc = 0.f;
    for (int d0 = 0; d0 < 512; d0 += 128) {
#pragma unroll
        for (int u = 0; u < 2; ++u) {
            int fi = tid + u * 256;
            int r = fi >> 5, c4 = fi & 31;
            *reinterpret_cast<float4*>(&ms[r][c4 * 4]) =
                *reinterpret_cast<const float4*>(&mem[(size_t)(t0 + r) * 512 + d0 + c4 * 4]);
            *reinterpret_cast<float4*>(&dsh[r][c4 * 4]) =
                *reinterpret_cast<const float4*>(&dec[(size_t)(b0 + r) * 512 + d0 + c4 * 4]);
        }
        if (tid < 32)
            *reinterpret_cast<float4*>(&vs[tid * 4]) =
                *reinterpret_cast<const float4*>(&vw[d0 + tid * 4]);
        __syncthreads();
#pragma unroll 8
        for (int j = 0; j < 128; j += 4) {
            float4 mv = *reinterpret_cast<const float4*>(&ms[tl][j]);
            float4 dv = *reinterpret_cast<const float4*>(&dsh[bl][j]);
            float4 wv = *reinterpret_cast<const float4*>(&vs[j]);
            acc += wv.x * fast_tanh(mv.x + dv.x);
            acc += wv.y * fast_tanh(mv.y + dv.y);
            acc += wv.z * fast_tanh(mv.z + dv.z);
            acc += wv.w * fast_tanh(mv.w + dv.w);
        }
        __syncthreads();
    }
    scores[(size_t)(b0 + bl) * 512 + (t0 + tl)] = acc;
}

// ---------------------------------------------------------------------------
// softmax over TK per row + c_t = attn @ mem.  8 rows per block, grid 64.
// ---------------------------------------------------------------------------
__global__ __launch_bounds__(256) void softmax_ct(const float* __restrict__ scores,
                                                  const float* __restrict__ mem,
                                                  float* __restrict__ attn_out,
                                                  float* __restrict__ ct_out) {
    __shared__ float sl[8][512];
    const int tid = threadIdx.x;
    const int b0 = blockIdx.x * 8;
#pragma unroll
    for (int i = 0; i < 16; ++i) {
        int idx = tid + i * 256;
        int r = idx >> 9, c = idx & 511;
        sl[r][c] = scores[(size_t)(b0 + r) * 512 + c];
    }
    __syncthreads();
    {
        int r = tid >> 5, li = tid & 31;
        float mx = -1e30f;
#pragma unroll
        for (int k = 0; k < 16; ++k) mx = fmaxf(mx, sl[r][li + k * 32]);
#pragma unroll
        for (int m = 1; m < 32; m <<= 1) mx = fmaxf(mx, __shfl_xor(mx, m));
        float pv[16];
        float sum = 0.f;
#pragma unroll
        for (int k = 0; k < 16; ++k) {
            float p = __expf(sl[r][li + k * 32] - mx);
            pv[k] = p;
            sum += p;
        }
#pragma unroll
        for (int m = 1; m < 32; m <<= 1) sum += __shfl_xor(sum, m);
        float inv = 1.f / sum;
#pragma unroll
        for (int k = 0; k < 16; ++k) {
            float a = pv[k] * inv;
            sl[r][li + k * 32] = a;
            attn_out[(size_t)(b0 + r) * 512 + li + k * 32] = a;
        }
    }
    __syncthreads();
    float acc[8][2] = {};
    const int d = tid;
    for (int t = 0; t < 512; ++t) {
        float m0v = mem[(size_t)t * 512 + d];
        float m1v = mem[(size_t)t * 512 + 256 + d];
#pragma unroll
        for (int r = 0; r < 8; ++r) {
            float a = sl[r][t];
            acc[r][0] += a * m0v;
            acc[r][1] += a * m1v;
        }
    }
#pragma unroll
    for (int r = 0; r < 8; ++r) {
        ct_out[(size_t)(b0 + r) * 512 + d] = acc[r][0];
        ct_out[(size_t)(b0 + r) * 512 + 256 + d] = acc[r][1];
    }
}

// --------------------------- small prep kernels ----------------------------
__global__ void prep_xcat(const int* __restrict__ y, const float* __restrict__ ct1,
                          const float* __restrict__ emb, float* __restrict__ xcat) {
    int b = blockIdx.x, tid = threadIdx.x;
    int yb = y[b];
    for (int j = tid; j < 768; j += 256)
        xcat[(size_t)b * 768 + j] = (j < 512) ? ct1[(size_t)b * 512 + j]
                                              : emb[(size_t)yb * 256 + (j - 512)];
}

__global__ void prep_wcat(const float* __restrict__ wih, const float* __restrict__ whh,
                          const float* __restrict__ bih, const float* __restrict__ bhh,
                          float* __restrict__ wcat, float* __restrict__ bsum) {
    int g = blockIdx.x, tid = threadIdx.x;
    for (int j = tid; j < 512; j += 256)
        wcat[(size_t)g * 512 + j] = (j < 256) ? wih[(size_t)g * 256 + j]
                                              : whh[(size_t)g * 256 + (j - 256)];
    if (tid == 0) bsum[g] = bih[g] + bhh[g];
}

__global__ void prep_xh(const float* __restrict__ x, const float* __restrict__ h0,
                        float* __restrict__ xh) {
    int b = blockIdx.x, tid = threadIdx.x;
    for (int j = tid; j < 512; j += 256)
        xh[(size_t)b * 512 + j] = (j < 256) ? x[(size_t)b * 256 + j]
                                            : h0[(size_t)b * 256 + (j - 256)];
}

__global__ void lstm_pw(const float* __restrict__ gates, const float* __restrict__ c0,
                        float* __restrict__ outH, float* __restrict__ outC,
                        float* __restrict__ scat) {
    int idx = blockIdx.x * 256 + threadIdx.x;   // 512*256
    int b = idx >> 8, j = idx & 255;
    const float* g = gates + (size_t)b * 1024;
    float ig = fast_sig(g[j]);
    float fg = fast_sig(g[256 + j]);
    float gg = fast_tanh(g[512 + j]);
    float og = fast_sig(g[768 + j]);
    float c = fg * c0[idx] + ig * gg;
    float h = og * fast_tanh(c);
    outH[idx] = h;
    outC[idx] = c;
    scat[(size_t)b * 512 + j] = h;
    scat[(size_t)b * 512 + 256 + j] = c;
}

__global__ void prep_hc(const float* __restrict__ h, const float* __restrict__ ct,
                        float* __restrict__ hc) {
    int b = blockIdx.x, tid = threadIdx.x;
    for (int j = tid; j < 768; j += 256)
        hc[(size_t)b * 768 + j] = (j < 256) ? h[(size_t)b * 256 + j]
                                            : ct[(size_t)b * 512 + (j - 256)];
}

__global__ __launch_bounds__(256) void pgen_k(const float* __restrict__ ct,
                                              const float* __restrict__ scat,
                                              const float* __restrict__ x,
                                              const float* __restrict__ Wpg,
                                              const float* __restrict__ bpg,
                                              float* __restrict__ outPG,
                                              float* __restrict__ pgw) {
    int b = blockIdx.x, tid = threadIdx.x;
    float part = 0.f;
    for (int idx = tid; idx < 1280; idx += 256) {
        float wv = Wpg[idx];
        float xv;
        if (idx < 512) xv = ct[(size_t)b * 512 + idx];
        else if (idx < 1024) xv = scat[(size_t)b * 512 + idx - 512];
        else xv = x[(size_t)b * 256 + idx - 1024];
        part += wv * xv;
    }
    __shared__ float red[256];
    red[tid] = part;
    __syncthreads();
    for (int s = 128; s > 0; s >>= 1) {
        if (tid < s) red[tid] += red[tid + s];
        __syncthreads();
    }
    if (tid == 0) {
        float pgv = fast_sig(red[0] + bpg[0]);
        outPG[b] = pgv;
        pgw[b] = pgv;
    }
}

__global__ void rowsum_k(const float* __restrict__ ps, const float* __restrict__ pgw,
                         float* __restrict__ scalew, float* __restrict__ adw) {
    int b = blockIdx.x * 256 + threadIdx.x;
    if (b >= 512) return;
    float s = 0.f;
    for (int cb = 0; cb < NCB_; ++cb) {
        size_t o = ((size_t)cb * 512 + b) * 2;
        s += ps[o] + ps[o + 1];
    }
    float pgv = pgw[b];
    scalew[b] = pgv / s;
    adw[b] = 1.f - pgv;
}

__global__ void scale_k(float* __restrict__ outF, const float* __restrict__ scalew,
                        const float* __restrict__ ez) {
    int c4 = blockIdx.x * 256 + threadIdx.x;   // float4 index, row has 12516
    if (c4 >= 12516) return;
    int b = blockIdx.y;
    float4* f = reinterpret_cast<float4*>(outF + (size_t)b * VE_);
    if (c4 < 12500) {
        float s = scalew[b];
        float4 v = f[c4];
        v.x *= s; v.y *= s; v.z *= s; v.w *= s;
        f[c4] = v;
    } else {
        int c = c4 * 4 - V_;
        f[c4] = *reinterpret_cast<const float4*>(&ez[(size_t)b * NOOV_ + c]);
    }
}

__global__ void scatter_k(const int* __restrict__ ebev, const float* __restrict__ attn,
                          const float* __restrict__ adw, float* __restrict__ outF) {
    int b = blockIdx.x, tid = threadIdx.x;
    float ad = adw[b];
    for (int t = tid; t < 512; t += 256) {
        int col = ebev[(size_t)b * 512 + t];
        float val = ad * attn[(size_t)b * 512 + t];
        atomicAdd(&outF[(size_t)b * VE_ + col], val);
    }
}

__global__ void copy_cov(const float* __restrict__ cov, float* __restrict__ out) {
    int i = blockIdx.x * 256 + threadIdx.x;
    reinterpret_cast<float4*>(out)[i] = reinterpret_cast<const float4*>(cov)[i];
}

// ---------------------------------------------------------------------------
extern "C" void kernel_launch(void* const* d_in, const int* in_sizes, int n_in,
                              void* d_out, int out_size, void* d_ws, size_t ws_size,
                              hipStream_t stream) {
    const int*   y    = (const int*)d_in[0];
    const float* h0   = (const float*)d_in[1];
    const float* c0   = (const float*)d_in[2];
    const float* ct1  = (const float*)d_in[3];
    const float* ez   = (const float*)d_in[4];
    const int*   ebev = (const int*)d_in[5];
    const float* cov  = (const float*)d_in[6];
    const float* emb  = (const float*)d_in[7];
    const float* Wx   = (const float*)d_in[8];
    const float* bx   = (const float*)d_in[9];
    const float* Wih  = (const float*)d_in[10];
    const float* Whh  = (const float*)d_in[11];
    const float* bih  = (const float*)d_in[12];
    const float* bhh  = (const float*)d_in[13];
    const float* memp = (const float*)d_in[14];
    const float* Wdp  = (const float*)d_in[15];
    const float* bdp  = (const float*)d_in[16];
    const float* vw   = (const float*)d_in[17];
    const float* Wpg  = (const float*)d_in[18];
    const float* bpg  = (const float*)d_in[19];
    const float* Wo1  = (const float*)d_in[20];
    const float* bo1  = (const float*)d_in[21];
    const float* Wo2  = (const float*)d_in[22];
    const float* bo2  = (const float*)d_in[23];

    float* out = (float*)d_out;
    // output layout (floats)
    const size_t OUT_FINAL = 0;
    const size_t OUT_H    = (size_t)B_ * VE_;
    const size_t OUT_C    = OUT_H + (size_t)B_ * H_;
    const size_t OUT_CT   = OUT_C + (size_t)B_ * H_;
    const size_t OUT_ATTN = OUT_CT + (size_t)B_ * 2 * H_;
    const size_t OUT_PG   = OUT_ATTN + (size_t)B_ * TK_;
    const size_t OUT_COV  = OUT_PG + B_;

    // workspace layout (floats)
    float* w = (float*)d_ws;
    float* xcat  = w;                       // 512*768
    float* xw    = xcat + 512 * 768;        // 512*256
    float* Wcat  = xw + 512 * 256;          // 1024*512
    float* bsum  = Wcat + 1024 * 512;       // 1024
    float* xh    = bsum + 1024;             // 512*512
    float* gates = xh + 512 * 512;          // 512*1024
    float* scat  = gates + 512 * 1024;      // 512*512
    float* dec   = scat + 512 * 512;        // 512*512
    float* scores= dec + 512 * 512;         // 512*512
    float* hc    = scores + 512 * 512;      // 512*768
    float* out1  = hc + 512 * 768;          // 512*256
    float* ps    = out1 + 512 * 256;        // 391*512*2
    float* pgw   = ps + (size_t)NCB_ * 512 * 2;   // 512
    float* scalew= pgw + 512;               // 512
    float* adw   = scalew + 512;            // 512

    // 1) x = cat(c_t_1, emb[y]) @ Wx^T + bx
    prep_xcat<<<512, 256, 0, stream>>>(y, ct1, emb, xcat);
    prep_wcat<<<1024, 256, 0, stream>>>(Wih, Whh, bih, bhh, Wcat, bsum);
    gemm_bt<0><<<dim3(2, 4), 256, 0, stream>>>(xcat, Wx, bx, xw, 256, 768);

    // 2) LSTM cell
    prep_xh<<<512, 256, 0, stream>>>(xw, h0, xh);
    gemm_bt<0><<<dim3(8, 4), 256, 0, stream>>>(xh, Wcat, bsum, gates, 1024, 512);
    lstm_pw<<<512, 256, 0, stream>>>(gates, c0, out + OUT_H, out + OUT_C, scat);

    // 3) attention
    gemm_bt<0><<<dim3(4, 4), 256, 0, stream>>>(scat, Wdp, bdp, dec, 512, 512);
    attn_scores<<<dim3(32, 32), 256, 0, stream>>>(memp, dec, vw, scores);
    softmax_ct<<<64, 256, 0, stream>>>(scores, memp, out + OUT_ATTN, out + OUT_CT);

    // 4) p_gen
    pgen_k<<<512, 256, 0, stream>>>(out + OUT_CT, scat, xw, Wpg, bpg,
                                    out + OUT_PG, pgw);

    // 5) vocab distribution
    prep_hc<<<512, 256, 0, stream>>>(out + OUT_H, out + OUT_CT, hc);
    gemm_bt<1><<<dim3(2, 4), 256, 0, stream>>>(hc, Wo1, bo1, out1, 256, 768);
    gemm_exp<<<dim3(NCB_, 4), 256, 0, stream>>>(out1, Wo2, bo2, out + OUT_FINAL, ps);
    rowsum_k<<<2, 256, 0, stream>>>(ps, pgw, scalew, adw);
    scale_k<<<dim3(49, 512), 256, 0, stream>>>(out + OUT_FINAL, scalew, ez);

    // 6) scatter-add pointer distribution
    scatter_k<<<512, 256, 0, stream>>>(ebev, out + OUT_ATTN, adw, out + OUT_FINAL);

    // 7) coverage passthrough
    copy_cov<<<256, 256, 0, stream>>>(cov, out + OUT_COV);
}

// Round 2
// 297.223 us; speedup vs baseline: 1.6469x; 1.6469x over previous
//
#include <hip/hip_runtime.h>
#include <hip/hip_bf16.h>

// Problem constants
#define B_  512
#define H_  256
#define TK_ 512
#define V_  50000
#define NOOV_ 64
#define VE_ (V_ + NOOV_)   // 50064
#define NCB_ 391           // ceil(50000/128)

typedef __bf16 bf16_t;
typedef __bf16 bf16x8 __attribute__((ext_vector_type(8)));
typedef float  f32x4  __attribute__((ext_vector_type(4)));

#define DEVI __device__ __forceinline__

DEVI float fast_rcp(float x) { return __builtin_amdgcn_rcpf(x); }
DEVI float fast_tanh(float x) {
    float e = __expf(2.f * x);
    return 1.f - 2.f * fast_rcp(e + 1.f);
}
DEVI float fast_sig(float x) { return fast_rcp(1.f + __expf(-x)); }

DEVI unsigned f2bf1(float f) {
    unsigned u = __float_as_uint(f);
    return (u + 0x7fffu + ((u >> 16) & 1u)) >> 16;   // RNE
}
DEVI unsigned f2bf2(float lo, float hi) { return f2bf1(lo) | (f2bf1(hi) << 16); }

DEVI uint4 cvt8(const float* p) {
    float4 a = *reinterpret_cast<const float4*>(p);
    float4 b = *reinterpret_cast<const float4*>(p + 4);
    uint4 r;
    r.x = f2bf2(a.x, a.y); r.y = f2bf2(a.z, a.w);
    r.z = f2bf2(b.x, b.y); r.w = f2bf2(b.z, b.w);
    return r;
}

// ---------------------------------------------------------------------------
// Wo2 f32 -> bf16 (12.8M elems, 1.6M uint4 items), grid 6250x256 exact
// ---------------------------------------------------------------------------
__global__ __launch_bounds__(256) void conv_wo2(const float* __restrict__ src,
                                                unsigned short* __restrict__ dst) {
    int i = blockIdx.x * 256 + threadIdx.x;
    reinterpret_cast<uint4*>(dst)[i] = cvt8(src + (size_t)i * 8);
}

// ---------------------------------------------------------------------------
// All small conversions / gathers in one kernel (uint4-granular items)
// ---------------------------------------------------------------------------
#define PR_O1 24576    // Wx end
#define PR_O2 57344    // Wdp end
#define PR_O3 81920    // Wo1 end
#define PR_O4 147456   // Wcat end
#define PR_O5 196608   // xcat end
#define PR_O6 212992   // xh-h0 end
#define PR_END 213120  // bsum end

__global__ __launch_bounds__(256) void prep_small(
        const float* __restrict__ Wx, const float* __restrict__ Wdp,
        const float* __restrict__ Wo1,
        const float* __restrict__ Wih, const float* __restrict__ Whh,
        const float* __restrict__ bih, const float* __restrict__ bhh,
        const int* __restrict__ y, const float* __restrict__ ct1,
        const float* __restrict__ emb, const float* __restrict__ h0,
        unsigned short* __restrict__ Wx_bf, unsigned short* __restrict__ Wdp_bf,
        unsigned short* __restrict__ Wo1_bf, unsigned short* __restrict__ Wcat_bf,
        unsigned short* __restrict__ xcat_bf, unsigned short* __restrict__ xh_bf,
        float* __restrict__ bsum) {
    int idx = blockIdx.x * 256 + threadIdx.x;
    if (idx >= PR_END) return;
    if (idx < PR_O1) {
        reinterpret_cast<uint4*>(Wx_bf)[idx] = cvt8(Wx + (size_t)idx * 8);
    } else if (idx < PR_O2) {
        int i = idx - PR_O1;
        reinterpret_cast<uint4*>(Wdp_bf)[i] = cvt8(Wdp + (size_t)i * 8);
    } else if (idx < PR_O3) {
        int i = idx - PR_O2;
        reinterpret_cast<uint4*>(Wo1_bf)[i] = cvt8(Wo1 + (size_t)i * 8);
    } else if (idx < PR_O4) {
        int i = idx - PR_O3;
        int r = i >> 6, c = (i & 63) * 8;
        const float* src = (c < 256) ? &Wih[(size_t)r * 256 + c]
                                     : &Whh[(size_t)r * 256 + (c - 256)];
        *reinterpret_cast<uint4*>(&Wcat_bf[(size_t)r * 512 + c]) = cvt8(src);
    } else if (idx < PR_O5) {
        int i = idx - PR_O4;
        int b = i / 96, j = (i - b * 96) * 8;
        const float* src = (j < 512) ? &ct1[(size_t)b * 512 + j]
                                     : &emb[(size_t)y[b] * 256 + (j - 512)];
        *reinterpret_cast<uint4*>(&xcat_bf[(size_t)b * 768 + j]) = cvt8(src);
    } else if (idx < PR_O6) {
        int i = idx - PR_O5;
        int b = i >> 5, c = (i & 31) * 8;
        *reinterpret_cast<uint4*>(&xh_bf[(size_t)b * 512 + 256 + c]) =
            cvt8(&h0[(size_t)b * 256 + c]);
    } else {
        int g0 = (idx - PR_O6) * 8;
#pragma unroll
        for (int k = 0; k < 8; ++k) bsum[g0 + k] = bih[g0 + k] + bhh[g0 + k];
    }
}

// ---------------------------------------------------------------------------
// Small GEMM: C[M,N] = A[M,K](bf16) * B[N,K]^T(bf16) + bias
// BM=BN=64, BK=64, 256 threads (4 waves 2x2, each 32x32 = 2x2 frags)
// grid (N/64, M/64). Optional f32 out Cf[.,N], optional bf16 out Cb (ldcb,ocb).
// ---------------------------------------------------------------------------
__global__ __launch_bounds__(256) void gemm64(const unsigned short* __restrict__ Abf,
                                              const unsigned short* __restrict__ Bbf,
                                              const float* __restrict__ bias,
                                              float* __restrict__ Cf,
                                              unsigned short* __restrict__ Cb,
                                              int N, int K, int ldcb, int ocb,
                                              int relu) {
    __shared__ unsigned short As[64][72];
    __shared__ unsigned short Bs[64][72];
    const int tid = threadIdx.x;
    const int m0 = blockIdx.y * 64;
    const int n0 = blockIdx.x * 64;
    const int lane = tid & 63;
    const int wid = tid >> 6;
    const int wm = wid >> 1, wn = wid & 1;

    f32x4 acc[2][2] = {};

    for (int k0 = 0; k0 < K; k0 += 64) {
#pragma unroll
        for (int i = 0; i < 2; ++i) {
            int idx = tid + i * 256;       // 512 uint4 slots
            int r = idx >> 3;
            int c = (idx & 7) * 8;
            *reinterpret_cast<uint4*>(&As[r][c]) =
                *reinterpret_cast<const uint4*>(&Abf[(size_t)(m0 + r) * K + k0 + c]);
            *reinterpret_cast<uint4*>(&Bs[r][c]) =
                *reinterpret_cast<const uint4*>(&Bbf[(size_t)(n0 + r) * K + k0 + c]);
        }
        __syncthreads();
#pragma unroll
        for (int ks = 0; ks < 64; ks += 32) {
            int koff = ks + (lane >> 4) * 8;
            bf16x8 af[2], bfv[2];
#pragma unroll
            for (int mi = 0; mi < 2; ++mi)
                af[mi] = *reinterpret_cast<const bf16x8*>(&As[wm * 32 + mi * 16 + (lane & 15)][koff]);
#pragma unroll
            for (int ni = 0; ni < 2; ++ni)
                bfv[ni] = *reinterpret_cast<const bf16x8*>(&Bs[wn * 32 + ni * 16 + (lane & 15)][koff]);
#pragma unroll
            for (int mi = 0; mi < 2; ++mi)
#pragma unroll
                for (int ni = 0; ni < 2; ++ni)
                    acc[mi][ni] = __builtin_amdgcn_mfma_f32_16x16x32_bf16(af[mi], bfv[ni], acc[mi][ni], 0, 0, 0);
        }
        __syncthreads();
    }

#pragma unroll
    for (int mi = 0; mi < 2; ++mi)
#pragma unroll
        for (int ni = 0; ni < 2; ++ni) {
            int c = n0 + wn * 32 + ni * 16 + (lane & 15);
            float bv = bias[c];
#pragma unroll
            for (int r = 0; r < 4; ++r) {
                int rr = m0 + wm * 32 + mi * 16 + (lane >> 4) * 4 + r;
                float v = acc[mi][ni][r] + bv;
                if (relu) v = fmaxf(v, 0.f);
                if (Cf) Cf[(size_t)rr * N + c] = v;
                if (Cb) Cb[(size_t)rr * ldcb + ocb + c] = (unsigned short)f2bf1(v);
            }
        }
}

// ---------------------------------------------------------------------------
// Big GEMM: exp(out1[512,256] @ Wo2[50000,256]^T + bo2) -> outF (unscaled) +
// per-(colblock,row,wave-n) partial sums. bf16 inputs, BK=128.
// grid (4, 391): x = row-block (fastest -> 4 consecutive blocks share B tile)
// ---------------------------------------------------------------------------
__global__ __launch_bounds__(256) void gemm_exp(const unsigned short* __restrict__ Abf,
                                                const unsigned short* __restrict__ Bbf,
                                                const float* __restrict__ bo2,
                                                float* __restrict__ outF,
                                                float* __restrict__ ps) {
    __shared__ unsigned short As[128][136];
    __shared__ unsigned short Bs[128][136];
    const int tid = threadIdx.x;
    const int m0 = blockIdx.x * 128;
    const int cb = blockIdx.y;
    const int n0 = cb * 128;
    const int lane = tid & 63;
    const int wid = tid >> 6;
    const int wm = wid >> 1, wn = wid & 1;

    f32x4 acc[4][4] = {};

    for (int k0 = 0; k0 < 256; k0 += 128) {
#pragma unroll
        for (int i = 0; i < 8; ++i) {
            int idx = tid + i * 256;       // 2048 uint4 per matrix
            int r = idx >> 4;
            int c = (idx & 15) * 8;
            *reinterpret_cast<uint4*>(&As[r][c]) =
                *reinterpret_cast<const uint4*>(&Abf[(size_t)(m0 + r) * 256 + k0 + c]);
            uint4 vb = make_uint4(0u, 0u, 0u, 0u);
            if (n0 + r < V_)
                vb = *reinterpret_cast<const uint4*>(&Bbf[(size_t)(n0 + r) * 256 + k0 + c]);
            *reinterpret_cast<uint4*>(&Bs[r][c]) = vb;
        }
        __syncthreads();
#pragma unroll
        for (int ks = 0; ks < 128; ks += 32) {
            int koff = ks + (lane >> 4) * 8;
            bf16x8 af[4], bfv[4];
#pragma unroll
            for (int mi = 0; mi < 4; ++mi)
                af[mi] = *reinterpret_cast<const bf16x8*>(&As[wm * 64 + mi * 16 + (lane & 15)][koff]);
#pragma unroll
            for (int ni = 0; ni < 4; ++ni)
                bfv[ni] = *reinterpret_cast<const bf16x8*>(&Bs[wn * 64 + ni * 16 + (lane & 15)][koff]);
#pragma unroll
            for (int mi = 0; mi < 4; ++mi)
#pragma unroll
                for (int ni = 0; ni < 4; ++ni)
                    acc[mi][ni] = __builtin_amdgcn_mfma_f32_16x16x32_bf16(af[mi], bfv[ni], acc[mi][ni], 0, 0, 0);
        }
        __syncthreads();
    }

    float psum[4][4];
#pragma unroll
    for (int mi = 0; mi < 4; ++mi)
#pragma unroll
        for (int r = 0; r < 4; ++r) psum[mi][r] = 0.f;

#pragma unroll
    for (int mi = 0; mi < 4; ++mi)
#pragma unroll
        for (int ni = 0; ni < 4; ++ni) {
            int c = n0 + wn * 64 + ni * 16 + (lane & 15);
            bool ok = (c < V_);
            float bv = ok ? bo2[c] : 0.f;
#pragma unroll
            for (int r = 0; r < 4; ++r) {
                float p = 0.f;
                if (ok) {
                    int rr = m0 + wm * 64 + mi * 16 + (lane >> 4) * 4 + r;
                    p = __expf(acc[mi][ni][r] + bv);
                    outF[(size_t)rr * VE_ + c] = p;
                }
                psum[mi][r] += p;
            }
        }

#pragma unroll
    for (int mi = 0; mi < 4; ++mi)
#pragma unroll
        for (int r = 0; r < 4; ++r) {
            float v = psum[mi][r];
            v += __shfl_xor(v, 1);
            v += __shfl_xor(v, 2);
            v += __shfl_xor(v, 4);
            v += __shfl_xor(v, 8);
            if ((lane & 15) == 0) {
                int rr = m0 + wm * 64 + mi * 16 + (lane >> 4) * 4 + r;
                ps[((size_t)cb * 512 + rr) * 2 + wn] = v;
            }
        }
}

// ---------------------------------------------------------------------------
// scores[b,t] = sum_d tanh(mem[t,d] + dec[b,d]) * vw[d]   (d=512)
// ---------------------------------------------------------------------------
__global__ __launch_bounds__(256) void attn_scores(const float* __restrict__ mem,
                                                   const float* __restrict__ dec,
                                                   const float* __restrict__ vw,
                                                   float* __restrict__ scores) {
    __shared__ float ms[16][132];
    __shared__ float dsh[16][132];
    __shared__ float vs[128];
    const int tid = threadIdx.x;
    const int t0 = blockIdx.x * 16, b0 = blockIdx.y * 16;
    const int tl = tid & 15, bl = tid >> 4;
    float acc = 0.f;
    for (int d0 = 0; d0 < 512; d0 += 128) {
#pragma unroll
        for (int u = 0; u < 2; ++u) {
            int fi = tid + u * 256;
            int r = fi >> 5, c4 = fi & 31;
            *reinterpret_cast<float4*>(&ms[r][c4 * 4]) =
                *reinterpret_cast<const float4*>(&mem[(size_t)(t0 + r) * 512 + d0 + c4 * 4]);
            *reinterpret_cast<float4*>(&dsh[r][c4 * 4]) =
                *reinterpret_cast<const float4*>(&dec[(size_t)(b0 + r) * 512 + d0 + c4 * 4]);
        }
        if (tid < 32)
            *reinterpret_cast<float4*>(&vs[tid * 4]) =
                *reinterpret_cast<const float4*>(&vw[d0 + tid * 4]);
        __syncthreads();
#pragma unroll 8
        for (int j = 0; j < 128; j += 4) {
            float4 mv = *reinterpret_cast<const float4*>(&ms[tl][j]);
            float4 dv = *reinterpret_cast<const float4*>(&dsh[bl][j]);
            float4 wv = *reinterpret_cast<const float4*>(&vs[j]);
            acc += wv.x * fast_tanh(mv.x + dv.x);
            acc += wv.y * fast_tanh(mv.y + dv.y);
            acc += wv.z * fast_tanh(mv.z + dv.z);
            acc += wv.w * fast_tanh(mv.w + dv.w);
        }
        __syncthreads();
    }
    scores[(size_t)(b0 + bl) * 512 + (t0 + tl)] = acc;
}

// ---------------------------------------------------------------------------
// softmax over TK per row + c_t = attn @ mem; also writes bf16 ct into hc_bf
// ---------------------------------------------------------------------------
__global__ __launch_bounds__(256) void softmax_ct(const float* __restrict__ scores,
                                                  const float* __restrict__ mem,
                                                  float* __restrict__ attn_out,
                                                  float* __restrict__ ct_out,
                                                  unsigned short* __restrict__ hc_bf) {
    __shared__ float sl[8][512];
    const int tid = threadIdx.x;
    const int b0 = blockIdx.x * 8;
#pragma unroll
    for (int i = 0; i < 16; ++i) {
        int idx = tid + i * 256;
        int r = idx >> 9, c = idx & 511;
        sl[r][c] = scores[(size_t)(b0 + r) * 512 + c];
    }
    __syncthreads();
    {
        int r = tid >> 5, li = tid & 31;
        float mx = -1e30f;
#pragma unroll
        for (int k = 0; k < 16; ++k) mx = fmaxf(mx, sl[r][li + k * 32]);
#pragma unroll
        for (int m = 1; m < 32; m <<= 1) mx = fmaxf(mx, __shfl_xor(mx, m));
        float pv[16];
        float sum = 0.f;
#pragma unroll
        for (int k = 0; k < 16; ++k) {
            float p = __expf(sl[r][li + k * 32] - mx);
            pv[k] = p;
            sum += p;
        }
#pragma unroll
        for (int m = 1; m < 32; m <<= 1) sum += __shfl_xor(sum, m);
        float inv = 1.f / sum;
#pragma unroll
        for (int k = 0; k < 16; ++k) {
            float a = pv[k] * inv;
            sl[r][li + k * 32] = a;
            attn_out[(size_t)(b0 + r) * 512 + li + k * 32] = a;
        }
    }
    __syncthreads();
    float acc[8][2] = {};
    const int d = tid;
    for (int t = 0; t < 512; ++t) {
        float m0v = mem[(size_t)t * 512 + d];
        float m1v = mem[(size_t)t * 512 + 256 + d];
#pragma unroll
        for (int r = 0; r < 8; ++r) {
            float a = sl[r][t];
            acc[r][0] += a * m0v;
            acc[r][1] += a * m1v;
        }
    }
#pragma unroll
    for (int r = 0; r < 8; ++r) {
        int b = b0 + r;
        ct_out[(size_t)b * 512 + d] = acc[r][0];
        ct_out[(size_t)b * 512 + 256 + d] = acc[r][1];
        hc_bf[(size_t)b * 768 + 256 + d] = (unsigned short)f2bf1(acc[r][0]);
        hc_bf[(size_t)b * 768 + 512 + d] = (unsigned short)f2bf1(acc[r][1]);
    }
}

// ---------------------------------------------------------------------------
__global__ void lstm_pw(const float* __restrict__ gates, const float* __restrict__ c0,
                        float* __restrict__ outH, float* __restrict__ outC,
                        float* __restrict__ scat, unsigned short* __restrict__ scat_bf,
                        unsigned short* __restrict__ hc_bf) {
    int idx = blockIdx.x * 256 + threadIdx.x;   // 512*256
    int b = idx >> 8, j = idx & 255;
    const float* g = gates + (size_t)b * 1024;
    float ig = fast_sig(g[j]);
    float fg = fast_sig(g[256 + j]);
    float gg = fast_tanh(g[512 + j]);
    float og = fast_sig(g[768 + j]);
    float c = fg * c0[idx] + ig * gg;
    float h = og * fast_tanh(c);
    outH[idx] = h;
    outC[idx] = c;
    scat[(size_t)b * 512 + j] = h;
    scat[(size_t)b * 512 + 256 + j] = c;
    unsigned short hb = (unsigned short)f2bf1(h);
    unsigned short cb = (unsigned short)f2bf1(c);
    scat_bf[(size_t)b * 512 + j] = hb;
    scat_bf[(size_t)b * 512 + 256 + j] = cb;
    hc_bf[(size_t)b * 768 + j] = hb;
}

__global__ __launch_bounds__(256) void pgen_k(const float* __restrict__ ct,
                                              const float* __restrict__ scat,
                                              const float* __restrict__ x,
                                              const float* __restrict__ Wpg,
                                              const float* __restrict__ bpg,
                                              float* __restrict__ outPG,
                                              float* __restrict__ pgw) {
    int b = blockIdx.x, tid = threadIdx.x;
    float part = 0.f;
    for (int idx = tid; idx < 1280; idx += 256) {
        float wv = Wpg[idx];
        float xv;
        if (idx < 512) xv = ct[(size_t)b * 512 + idx];
        else if (idx < 1024) xv = scat[(size_t)b * 512 + idx - 512];
        else xv = x[(size_t)b * 256 + idx - 1024];
        part += wv * xv;
    }
    __shared__ float red[256];
    red[tid] = part;
    __syncthreads();
    for (int s = 128; s > 0; s >>= 1) {
        if (tid < s) red[tid] += red[tid + s];
        __syncthreads();
    }
    if (tid == 0) {
        float pgv = fast_sig(red[0] + bpg[0]);
        outPG[b] = pgv;
        pgw[b] = pgv;
    }
}

// per-row: scale = pgen/sum over all colblocks; adw = 1-pgen.  512 blocks x 64
__global__ __launch_bounds__(64) void rowsum_k(const float* __restrict__ ps,
                                               const float* __restrict__ pgw,
                                               float* __restrict__ scalew,
                                               float* __restrict__ adw) {
    int b = blockIdx.x;
    int lane = threadIdx.x;
    float s = 0.f;
    for (int cb = lane; cb < NCB_; cb += 64) {
        size_t o = ((size_t)cb * 512 + b) * 2;
        s += ps[o] + ps[o + 1];
    }
#pragma unroll
    for (int m = 1; m < 64; m <<= 1) s += __shfl_xor(s, m);
    if (lane == 0) {
        float pgv = pgw[b];
        scalew[b] = pgv / s;
        adw[b] = 1.f - pgv;
    }
}

// ---------------------------------------------------------------------------
// Fused: scale exp row -> final, fill extra_zeros, copy coverage, scatter-add.
// One block per row, 512 threads.
// ---------------------------------------------------------------------------
__global__ __launch_bounds__(512) void final_fix(float* __restrict__ outF,
                                                 const float* __restrict__ scalew,
                                                 const float* __restrict__ adw,
                                                 const float* __restrict__ ez,
                                                 const float* __restrict__ attn,
                                                 const int* __restrict__ ebev,
                                                 const float* __restrict__ cov,
                                                 float* __restrict__ outCov) {
    const int b = blockIdx.x;
    const int tid = threadIdx.x;
    const float s = scalew[b];
    float4* f = reinterpret_cast<float4*>(outF + (size_t)b * VE_);
    for (int c4 = tid; c4 < 12516; c4 += 512) {
        if (c4 < 12500) {
            float4 v = f[c4];
            v.x *= s; v.y *= s; v.z *= s; v.w *= s;
            f[c4] = v;
        } else {
            f[c4] = *reinterpret_cast<const float4*>(&ez[(size_t)b * NOOV_ + (c4 - 12500) * 4]);
        }
    }
    if (tid < 128)
        reinterpret_cast<float4*>(outCov + (size_t)b * 512)[tid] =
            reinterpret_cast<const float4*>(cov + (size_t)b * 512)[tid];
    __syncthreads();
    {
        float ad = adw[b];
        int col = ebev[(size_t)b * 512 + tid];
        float val = ad * attn[(size_t)b * 512 + tid];
        atomicAdd(&outF[(size_t)b * VE_ + col], val);
    }
}

// ---------------------------------------------------------------------------
extern "C" void kernel_launch(void* const* d_in, const int* in_sizes, int n_in,
                              void* d_out, int out_size, void* d_ws, size_t ws_size,
                              hipStream_t stream) {
    const int*   y    = (const int*)d_in[0];
    const float* h0   = (const float*)d_in[1];
    const float* c0   = (const float*)d_in[2];
    const float* ct1  = (const float*)d_in[3];
    const float* ez   = (const float*)d_in[4];
    const int*   ebev = (const int*)d_in[5];
    const float* cov  = (const float*)d_in[6];
    const float* emb  = (const float*)d_in[7];
    const float* Wx   = (const float*)d_in[8];
    const float* bx   = (const float*)d_in[9];
    const float* Wih  = (const float*)d_in[10];
    const float* Whh  = (const float*)d_in[11];
    const float* bih  = (const float*)d_in[12];
    const float* bhh  = (const float*)d_in[13];
    const float* memp = (const float*)d_in[14];
    const float* Wdp  = (const float*)d_in[15];
    const float* bdp  = (const float*)d_in[16];
    const float* vw   = (const float*)d_in[17];
    const float* Wpg  = (const float*)d_in[18];
    const float* bpg  = (const float*)d_in[19];
    const float* Wo1  = (const float*)d_in[20];
    const float* bo1  = (const float*)d_in[21];
    const float* Wo2  = (const float*)d_in[22];
    const float* bo2  = (const float*)d_in[23];

    float* out = (float*)d_out;
    const size_t OUT_FINAL = 0;
    const size_t OUT_H    = (size_t)B_ * VE_;
    const size_t OUT_C    = OUT_H + (size_t)B_ * H_;
    const size_t OUT_CT   = OUT_C + (size_t)B_ * H_;
    const size_t OUT_ATTN = OUT_CT + (size_t)B_ * 2 * H_;
    const size_t OUT_PG   = OUT_ATTN + (size_t)B_ * TK_;
    const size_t OUT_COV  = OUT_PG + B_;

    // ---- workspace layout ----
    char* wb = (char*)d_ws;
    // f32 region
    float* xw     = (float*)wb;                       // 131072
    float* gates  = xw + 131072;                      // 524288
    float* scat   = gates + 524288;                   // 262144
    float* dec    = scat + 262144;                    // 262144
    float* scores = dec + 262144;                     // 262144
    float* ps     = scores + 262144;                  // 400384
    float* bsum   = ps + 400384;                      // 1024
    float* pgw    = bsum + 1024;                      // 512
    float* scalew = pgw + 512;                        // 512
    float* adw    = scalew + 512;                     // 512
    // bf16 region
    unsigned short* Wx_bf   = (unsigned short*)(adw + 512);
    unsigned short* Wcat_bf = Wx_bf + 196608;
    unsigned short* Wdp_bf  = Wcat_bf + 524288;
    unsigned short* Wo1_bf  = Wdp_bf + 262144;
    unsigned short* Wo2_bf  = Wo1_bf + 196608;
    unsigned short* xcat_bf = Wo2_bf + 12800000;
    unsigned short* xh_bf   = xcat_bf + 393216;
    unsigned short* scat_bf = xh_bf + 262144;
    unsigned short* hc_bf   = scat_bf + 262144;
    unsigned short* out1_bf = hc_bf + 393216;

    // 0) conversions
    conv_wo2<<<6250, 256, 0, stream>>>(Wo2, Wo2_bf);
    prep_small<<<(PR_END + 255) / 256, 256, 0, stream>>>(
        Wx, Wdp, Wo1, Wih, Whh, bih, bhh, y, ct1, emb, h0,
        Wx_bf, Wdp_bf, Wo1_bf, Wcat_bf, xcat_bf, xh_bf, bsum);

    // 1) x = cat(c_t_1, emb[y]) @ Wx^T + bx  -> f32 xw + bf16 into xh_bf[:,0:256]
    gemm64<<<dim3(4, 8), 256, 0, stream>>>(xcat_bf, Wx_bf, bx, xw, xh_bf,
                                           256, 768, 512, 0, 0);

    // 2) LSTM gates + pointwise
    gemm64<<<dim3(16, 8), 256, 0, stream>>>(xh_bf, Wcat_bf, bsum, gates, nullptr,
                                            1024, 512, 0, 0, 0);
    lstm_pw<<<512, 256, 0, stream>>>(gates, c0, out + OUT_H, out + OUT_C,
                                     scat, scat_bf, hc_bf);

    // 3) attention
    gemm64<<<dim3(8, 8), 256, 0, stream>>>(scat_bf, Wdp_bf, bdp, dec, nullptr,
                                           512, 512, 0, 0, 0);
    attn_scores<<<dim3(32, 32), 256, 0, stream>>>(memp, dec, vw, scores);
    softmax_ct<<<64, 256, 0, stream>>>(scores, memp, out + OUT_ATTN, out + OUT_CT,
                                       hc_bf);

    // 4) p_gen
    pgen_k<<<512, 256, 0, stream>>>(out + OUT_CT, scat, xw, Wpg, bpg,
                                    out + OUT_PG, pgw);

    // 5) vocab distribution
    gemm64<<<dim3(4, 8), 256, 0, stream>>>(hc_bf, Wo1_bf, bo1, nullptr, out1_bf,
                                           256, 768, 256, 0, 1);
    gemm_exp<<<dim3(4, NCB_), 256, 0, stream>>>(out1_bf, Wo2_bf, bo2,
                                                out + OUT_FINAL, ps);
    rowsum_k<<<512, 64, 0, stream>>>(ps, pgw, scalew, adw);

    // 6) fused scale + extra_zeros + coverage + scatter
    final_fix<<<512, 512, 0, stream>>>(out + OUT_FINAL, scalew, adw, ez,
                                       out + OUT_ATTN, ebev, cov, out + OUT_COV);
}

// Round 3
// 267.230 us; speedup vs baseline: 1.8318x; 1.1122x over previous
//
#include <hip/hip_runtime.h>
#include <hip/hip_bf16.h>

// Problem constants
#define B_  512
#define H_  256
#define TK_ 512
#define V_  50000
#define NOOV_ 64
#define VE_ (V_ + NOOV_)   // 50064
#define NCB_ 391           // ceil(50000/128)
#define ELOFF 25032        // float offset of bf16 exp-stash inside each out row

typedef __bf16 bf16_t;
typedef __bf16 bf16x8 __attribute__((ext_vector_type(8)));
typedef float  f32x4  __attribute__((ext_vector_type(4)));

#define DEVI __device__ __forceinline__

DEVI float fast_rcp(float x) { return __builtin_amdgcn_rcpf(x); }
DEVI float fast_tanh(float x) {
    float e = __expf(2.f * x);
    return 1.f - 2.f * fast_rcp(e + 1.f);
}
DEVI float fast_sig(float x) { return fast_rcp(1.f + __expf(-x)); }

DEVI unsigned f2bf1(float f) {
    unsigned u = __float_as_uint(f);
    return (u + 0x7fffu + ((u >> 16) & 1u)) >> 16;   // RNE
}
DEVI unsigned f2bf2(float lo, float hi) { return f2bf1(lo) | (f2bf1(hi) << 16); }

DEVI uint4 cvt8(const float* p) {
    float4 a = *reinterpret_cast<const float4*>(p);
    float4 b = *reinterpret_cast<const float4*>(p + 4);
    uint4 r;
    r.x = f2bf2(a.x, a.y); r.y = f2bf2(a.z, a.w);
    r.z = f2bf2(b.x, b.y); r.w = f2bf2(b.z, b.w);
    return r;
}

// ---------------------------------------------------------------------------
// All small conversions / gathers in one kernel (uint4-granular items)
// ---------------------------------------------------------------------------
#define PR_O1 24576    // Wx end
#define PR_O2 57344    // Wdp end
#define PR_O3 81920    // Wo1 end
#define PR_O4 147456   // Wcat end
#define PR_O5 196608   // xcat end
#define PR_O6 212992   // xh-h0 end
#define PR_END 213120  // bsum end

__global__ __launch_bounds__(256) void prep_small(
        const float* __restrict__ Wx, const float* __restrict__ Wdp,
        const float* __restrict__ Wo1,
        const float* __restrict__ Wih, const float* __restrict__ Whh,
        const float* __restrict__ bih, const float* __restrict__ bhh,
        const int* __restrict__ y, const float* __restrict__ ct1,
        const float* __restrict__ emb, const float* __restrict__ h0,
        unsigned short* __restrict__ Wx_bf, unsigned short* __restrict__ Wdp_bf,
        unsigned short* __restrict__ Wo1_bf, unsigned short* __restrict__ Wcat_bf,
        unsigned short* __restrict__ xcat_bf, unsigned short* __restrict__ xh_bf,
        float* __restrict__ bsum) {
    int idx = blockIdx.x * 256 + threadIdx.x;
    if (idx >= PR_END) return;
    if (idx < PR_O1) {
        reinterpret_cast<uint4*>(Wx_bf)[idx] = cvt8(Wx + (size_t)idx * 8);
    } else if (idx < PR_O2) {
        int i = idx - PR_O1;
        reinterpret_cast<uint4*>(Wdp_bf)[i] = cvt8(Wdp + (size_t)i * 8);
    } else if (idx < PR_O3) {
        int i = idx - PR_O2;
        reinterpret_cast<uint4*>(Wo1_bf)[i] = cvt8(Wo1 + (size_t)i * 8);
    } else if (idx < PR_O4) {
        int i = idx - PR_O3;
        int r = i >> 6, c = (i & 63) * 8;
        const float* src = (c < 256) ? &Wih[(size_t)r * 256 + c]
                                     : &Whh[(size_t)r * 256 + (c - 256)];
        *reinterpret_cast<uint4*>(&Wcat_bf[(size_t)r * 512 + c]) = cvt8(src);
    } else if (idx < PR_O5) {
        int i = idx - PR_O4;
        int b = i / 96, j = (i - b * 96) * 8;
        const float* src = (j < 512) ? &ct1[(size_t)b * 512 + j]
                                     : &emb[(size_t)y[b] * 256 + (j - 512)];
        *reinterpret_cast<uint4*>(&xcat_bf[(size_t)b * 768 + j]) = cvt8(src);
    } else if (idx < PR_O6) {
        int i = idx - PR_O5;
        int b = i >> 5, c = (i & 31) * 8;
        *reinterpret_cast<uint4*>(&xh_bf[(size_t)b * 512 + 256 + c]) =
            cvt8(&h0[(size_t)b * 256 + c]);
    } else {
        int g0 = (idx - PR_O6) * 8;
#pragma unroll
        for (int k = 0; k < 8; ++k) bsum[g0 + k] = bih[g0 + k] + bhh[g0 + k];
    }
}

// ---------------------------------------------------------------------------
// Small GEMM: C[M,N] = A[M,K](bf16) * B[N,K]^T(bf16) + bias
// BM=BN=64, BK=64, 256 threads (4 waves 2x2, each 32x32 = 2x2 frags)
// ---------------------------------------------------------------------------
__global__ __launch_bounds__(256) void gemm64(const unsigned short* __restrict__ Abf,
                                              const unsigned short* __restrict__ Bbf,
                                              const float* __restrict__ bias,
                                              float* __restrict__ Cf,
                                              unsigned short* __restrict__ Cb,
                                              int N, int K, int ldcb, int ocb,
                                              int relu) {
    __shared__ unsigned short As[64][72];
    __shared__ unsigned short Bs[64][72];
    const int tid = threadIdx.x;
    const int m0 = blockIdx.y * 64;
    const int n0 = blockIdx.x * 64;
    const int lane = tid & 63;
    const int wid = tid >> 6;
    const int wm = wid >> 1, wn = wid & 1;

    f32x4 acc[2][2] = {};

    for (int k0 = 0; k0 < K; k0 += 64) {
#pragma unroll
        for (int i = 0; i < 2; ++i) {
            int idx = tid + i * 256;       // 512 uint4 slots
            int r = idx >> 3;
            int c = (idx & 7) * 8;
            *reinterpret_cast<uint4*>(&As[r][c]) =
                *reinterpret_cast<const uint4*>(&Abf[(size_t)(m0 + r) * K + k0 + c]);
            *reinterpret_cast<uint4*>(&Bs[r][c]) =
                *reinterpret_cast<const uint4*>(&Bbf[(size_t)(n0 + r) * K + k0 + c]);
        }
        __syncthreads();
#pragma unroll
        for (int ks = 0; ks < 64; ks += 32) {
            int koff = ks + (lane >> 4) * 8;
            bf16x8 af[2], bfv[2];
#pragma unroll
            for (int mi = 0; mi < 2; ++mi)
                af[mi] = *reinterpret_cast<const bf16x8*>(&As[wm * 32 + mi * 16 + (lane & 15)][koff]);
#pragma unroll
            for (int ni = 0; ni < 2; ++ni)
                bfv[ni] = *reinterpret_cast<const bf16x8*>(&Bs[wn * 32 + ni * 16 + (lane & 15)][koff]);
#pragma unroll
            for (int mi = 0; mi < 2; ++mi)
#pragma unroll
                for (int ni = 0; ni < 2; ++ni)
                    acc[mi][ni] = __builtin_amdgcn_mfma_f32_16x16x32_bf16(af[mi], bfv[ni], acc[mi][ni], 0, 0, 0);
        }
        __syncthreads();
    }

#pragma unroll
    for (int mi = 0; mi < 2; ++mi)
#pragma unroll
        for (int ni = 0; ni < 2; ++ni) {
            int c = n0 + wn * 32 + ni * 16 + (lane & 15);
            float bv = bias[c];
#pragma unroll
            for (int r = 0; r < 4; ++r) {
                int rr = m0 + wm * 32 + mi * 16 + (lane >> 4) * 4 + r;
                float v = acc[mi][ni][r] + bv;
                if (relu) v = fmaxf(v, 0.f);
                if (Cf) Cf[(size_t)rr * N + c] = v;
                if (Cb) Cb[(size_t)rr * ldcb + ocb + c] = (unsigned short)f2bf1(v);
            }
        }
}

// ---------------------------------------------------------------------------
// Vocab GEMM pass 1: logits = out1[512,256](bf16) @ Wo2[50000,256]^T(f32,
// converted inline) + bo2.  Writes bf16 exp(logit) into the stash half of each
// output row + per-(colblock,row,half) partial sums (of the bf16-rounded
// values, so normalization is exactly consistent with final_write).
// 512 threads = 8 waves (4x2), BM=BN=128, BK=128, grid (4, 391).
// ---------------------------------------------------------------------------
__global__ __launch_bounds__(512) void gemm_sum(const unsigned short* __restrict__ Abf,
                                                const float* __restrict__ Wo2,
                                                const float* __restrict__ bo2,
                                                float* __restrict__ outF,
                                                float* __restrict__ ps) {
    __shared__ unsigned short As[128][136];
    __shared__ unsigned short Bs[128][136];
    const int tid = threadIdx.x;
    const int m0 = blockIdx.x * 128;
    const int cb = blockIdx.y;
    const int n0 = cb * 128;
    const int lane = tid & 63;
    const int wid = tid >> 6;
    const int wm = wid >> 1, wn = wid & 1;   // 4 x 2

    f32x4 acc[2][4] = {};

    for (int k0 = 0; k0 < 256; k0 += 128) {
#pragma unroll
        for (int i = 0; i < 4; ++i) {
            int idx = tid + i * 512;       // 2048 uint4 slots per matrix
            int r = idx >> 4;
            int c = (idx & 15) * 8;
            *reinterpret_cast<uint4*>(&As[r][c]) =
                *reinterpret_cast<const uint4*>(&Abf[(size_t)(m0 + r) * 256 + k0 + c]);
            uint4 vb = make_uint4(0u, 0u, 0u, 0u);
            if (n0 + r < V_)
                vb = cvt8(&Wo2[(size_t)(n0 + r) * 256 + k0 + c]);
            *reinterpret_cast<uint4*>(&Bs[r][c]) = vb;
        }
        __syncthreads();
#pragma unroll
        for (int ks = 0; ks < 128; ks += 32) {
            int koff = ks + (lane >> 4) * 8;
            bf16x8 af[2], bfv[4];
#pragma unroll
            for (int mi = 0; mi < 2; ++mi)
                af[mi] = *reinterpret_cast<const bf16x8*>(&As[wm * 32 + mi * 16 + (lane & 15)][koff]);
#pragma unroll
            for (int ni = 0; ni < 4; ++ni)
                bfv[ni] = *reinterpret_cast<const bf16x8*>(&Bs[wn * 64 + ni * 16 + (lane & 15)][koff]);
#pragma unroll
            for (int mi = 0; mi < 2; ++mi)
#pragma unroll
                for (int ni = 0; ni < 4; ++ni)
                    acc[mi][ni] = __builtin_amdgcn_mfma_f32_16x16x32_bf16(af[mi], bfv[ni], acc[mi][ni], 0, 0, 0);
        }
        __syncthreads();
    }

    float psum[2][4];
#pragma unroll
    for (int mi = 0; mi < 2; ++mi)
#pragma unroll
        for (int r = 0; r < 4; ++r) psum[mi][r] = 0.f;

#pragma unroll
    for (int mi = 0; mi < 2; ++mi)
#pragma unroll
        for (int ni = 0; ni < 4; ++ni) {
            int c = n0 + wn * 64 + ni * 16 + (lane & 15);
            bool ok = (c < V_);
            float bv = ok ? bo2[c] : 0.f;
#pragma unroll
            for (int r = 0; r < 4; ++r) {
                int rr = m0 + wm * 32 + mi * 16 + (lane >> 4) * 4 + r;
                float p = __expf(acc[mi][ni][r] + bv);
                unsigned eb = f2bf1(p);
                if (ok) {
                    unsigned short* el =
                        (unsigned short*)(outF + (size_t)rr * VE_ + ELOFF);
                    el[c] = (unsigned short)eb;
                    psum[mi][r] += __uint_as_float(eb << 16);
                }
            }
        }

#pragma unroll
    for (int mi = 0; mi < 2; ++mi)
#pragma unroll
        for (int r = 0; r < 4; ++r) {
            float v = psum[mi][r];
            v += __shfl_xor(v, 1);
            v += __shfl_xor(v, 2);
            v += __shfl_xor(v, 4);
            v += __shfl_xor(v, 8);
            if ((lane & 15) == 0) {
                int rr = m0 + wm * 32 + mi * 16 + (lane >> 4) * 4 + r;
                ps[((size_t)cb * 512 + rr) * 2 + wn] = v;
            }
        }
}

// ---------------------------------------------------------------------------
// scores[b,t] = sum_d tanh(mem[t,d] + dec[b,d]) * vw[d]   (d=512)
// ---------------------------------------------------------------------------
__global__ __launch_bounds__(256) void attn_scores(const float* __restrict__ mem,
                                                   const float* __restrict__ dec,
                                                   const float* __restrict__ vw,
                                                   float* __restrict__ scores) {
    __shared__ float ms[16][132];
    __shared__ float dsh[16][132];
    __shared__ float vs[128];
    const int tid = threadIdx.x;
    const int t0 = blockIdx.x * 16, b0 = blockIdx.y * 16;
    const int tl = tid & 15, bl = tid >> 4;
    float acc = 0.f;
    for (int d0 = 0; d0 < 512; d0 += 128) {
#pragma unroll
        for (int u = 0; u < 2; ++u) {
            int fi = tid + u * 256;
            int r = fi >> 5, c4 = fi & 31;
            *reinterpret_cast<float4*>(&ms[r][c4 * 4]) =
                *reinterpret_cast<const float4*>(&mem[(size_t)(t0 + r) * 512 + d0 + c4 * 4]);
            *reinterpret_cast<float4*>(&dsh[r][c4 * 4]) =
                *reinterpret_cast<const float4*>(&dec[(size_t)(b0 + r) * 512 + d0 + c4 * 4]);
        }
        if (tid < 32)
            *reinterpret_cast<float4*>(&vs[tid * 4]) =
                *reinterpret_cast<const float4*>(&vw[d0 + tid * 4]);
        __syncthreads();
#pragma unroll 8
        for (int j = 0; j < 128; j += 4) {
            float4 mv = *reinterpret_cast<const float4*>(&ms[tl][j]);
            float4 dv = *reinterpret_cast<const float4*>(&dsh[bl][j]);
            float4 wv = *reinterpret_cast<const float4*>(&vs[j]);
            acc += wv.x * fast_tanh(mv.x + dv.x);
            acc += wv.y * fast_tanh(mv.y + dv.y);
            acc += wv.z * fast_tanh(mv.z + dv.z);
            acc += wv.w * fast_tanh(mv.w + dv.w);
        }
        __syncthreads();
    }
    scores[(size_t)(b0 + bl) * 512 + (t0 + tl)] = acc;
}

// ---------------------------------------------------------------------------
// softmax over TK per row (8 rows/block, 64 blocks) -> attn_out (f32)
// ---------------------------------------------------------------------------
__global__ __launch_bounds__(256) void softmax_k(const float* __restrict__ scores,
                                                 float* __restrict__ attn_out) {
    __shared__ float sl[8][512];
    const int tid = threadIdx.x;
    const int b0 = blockIdx.x * 8;
#pragma unroll
    for (int i = 0; i < 16; ++i) {
        int idx = tid + i * 256;
        int r = idx >> 9, c = idx & 511;
        sl[r][c] = scores[(size_t)(b0 + r) * 512 + c];
    }
    __syncthreads();
    int r = tid >> 5, li = tid & 31;
    float mx = -1e30f;
#pragma unroll
    for (int k = 0; k < 16; ++k) mx = fmaxf(mx, sl[r][li + k * 32]);
#pragma unroll
    for (int m = 1; m < 32; m <<= 1) mx = fmaxf(mx, __shfl_xor(mx, m));
    float pv[16];
    float sum = 0.f;
#pragma unroll
    for (int k = 0; k < 16; ++k) {
        float p = __expf(sl[r][li + k * 32] - mx);
        pv[k] = p;
        sum += p;
    }
#pragma unroll
    for (int m = 1; m < 32; m <<= 1) sum += __shfl_xor(sum, m);
    float inv = 1.f / sum;
#pragma unroll
    for (int k = 0; k < 16; ++k)
        attn_out[(size_t)(b0 + r) * 512 + li + k * 32] = pv[k] * inv;
}

// ---------------------------------------------------------------------------
// c_t = attn @ mem.  grid (4 d-chunks, 64 b-chunks), 256 thr: 128 cols x 8 rows
// ---------------------------------------------------------------------------
__global__ __launch_bounds__(256) void ct_k(const float* __restrict__ attn,
                                            const float* __restrict__ mem,
                                            float* __restrict__ ct_out,
                                            unsigned short* __restrict__ hc_bf) {
    __shared__ float al[8][512];
    const int tid = threadIdx.x;
    const int d0 = blockIdx.x * 128;
    const int b0 = blockIdx.y * 8;
#pragma unroll
    for (int i = 0; i < 16; ++i) {
        int idx = tid + i * 256;
        int r = idx >> 9, c = idx & 511;
        al[r][c] = attn[(size_t)(b0 + r) * 512 + c];
    }
    __syncthreads();
    const int c = tid & 127;
    const int h = tid >> 7;            // 0/1 -> rows b0+h*4 .. b0+h*4+3
    float acc[4] = {0.f, 0.f, 0.f, 0.f};
    for (int t = 0; t < 512; t += 2) {
        float m0v = mem[(size_t)t * 512 + d0 + c];
        float m1v = mem[(size_t)(t + 1) * 512 + d0 + c];
#pragma unroll
        for (int r = 0; r < 4; ++r) {
            acc[r] += al[h * 4 + r][t] * m0v;
            acc[r] += al[h * 4 + r][t + 1] * m1v;
        }
    }
#pragma unroll
    for (int r = 0; r < 4; ++r) {
        int b = b0 + h * 4 + r;
        ct_out[(size_t)b * 512 + d0 + c] = acc[r];
        hc_bf[(size_t)b * 768 + 256 + d0 + c] = (unsigned short)f2bf1(acc[r]);
    }
}

// ---------------------------------------------------------------------------
__global__ void lstm_pw(const float* __restrict__ gates, const float* __restrict__ c0,
                        float* __restrict__ outH, float* __restrict__ outC,
                        float* __restrict__ scat, unsigned short* __restrict__ scat_bf,
                        unsigned short* __restrict__ hc_bf) {
    int idx = blockIdx.x * 256 + threadIdx.x;   // 512*256
    int b = idx >> 8, j = idx & 255;
    const float* g = gates + (size_t)b * 1024;
    float ig = fast_sig(g[j]);
    float fg = fast_sig(g[256 + j]);
    float gg = fast_tanh(g[512 + j]);
    float og = fast_sig(g[768 + j]);
    float c = fg * c0[idx] + ig * gg;
    float h = og * fast_tanh(c);
    outH[idx] = h;
    outC[idx] = c;
    scat[(size_t)b * 512 + j] = h;
    scat[(size_t)b * 512 + 256 + j] = c;
    unsigned short hb = (unsigned short)f2bf1(h);
    unsigned short cb = (unsigned short)f2bf1(c);
    scat_bf[(size_t)b * 512 + j] = hb;
    scat_bf[(size_t)b * 512 + 256 + j] = cb;
    hc_bf[(size_t)b * 768 + j] = hb;
}

__global__ __launch_bounds__(256) void pgen_k(const float* __restrict__ ct,
                                              const float* __restrict__ scat,
                                              const float* __restrict__ x,
                                              const float* __restrict__ Wpg,
                                              const float* __restrict__ bpg,
                                              float* __restrict__ outPG,
                                              float* __restrict__ pgw) {
    int b = blockIdx.x, tid = threadIdx.x;
    float part = 0.f;
    for (int idx = tid; idx < 1280; idx += 256) {
        float wv = Wpg[idx];
        float xv;
        if (idx < 512) xv = ct[(size_t)b * 512 + idx];
        else if (idx < 1024) xv = scat[(size_t)b * 512 + idx - 512];
        else xv = x[(size_t)b * 256 + idx - 1024];
        part += wv * xv;
    }
    __shared__ float red[256];
    red[tid] = part;
    __syncthreads();
    for (int s = 128; s > 0; s >>= 1) {
        if (tid < s) red[tid] += red[tid + s];
        __syncthreads();
    }
    if (tid == 0) {
        float pgv = fast_sig(red[0] + bpg[0]);
        outPG[b] = pgv;
        pgw[b] = pgv;
    }
}

// per-row: scale = pgen/sum over all colblocks; adw = 1-pgen.  512 blocks x 64
__global__ __launch_bounds__(64) void rowsum_k(const float* __restrict__ ps,
                                               const float* __restrict__ pgw,
                                               float* __restrict__ scalew,
                                               float* __restrict__ adw) {
    int b = blockIdx.x;
    int lane = threadIdx.x;
    float s = 0.f;
    for (int cb = lane; cb < NCB_; cb += 64) {
        size_t o = ((size_t)cb * 512 + b) * 2;
        s += ps[o] + ps[o + 1];
    }
#pragma unroll
    for (int m = 1; m < 64; m <<= 1) s += __shfl_xor(s, m);
    if (lane == 0) {
        float pgv = pgw[b];
        scalew[b] = pgv / s;
        adw[b] = 1.f - pgv;
    }
}

// ---------------------------------------------------------------------------
// Pass 2: read bf16 exp-stash of this row into regs, sync, write scaled f32
// row + extra_zeros. One block per row, 1024 threads (in-place safe).
// ---------------------------------------------------------------------------
__global__ __launch_bounds__(1024) void final_write(float* __restrict__ outF,
                                                    const float* __restrict__ scalew,
                                                    const float* __restrict__ ez) {
    const int b = blockIdx.x;
    const int tid = threadIdx.x;
    const float s = scalew[b];
    float* row = outF + (size_t)b * VE_;
    const unsigned short* el = (const unsigned short*)(row + ELOFF);

    uint2 buf[13];
    float4 ezbuf;
#pragma unroll
    for (int k = 0; k < 13; ++k) {
        int c4 = tid + (k << 10);
        if (c4 < 12500)
            buf[k] = *reinterpret_cast<const uint2*>(el + c4 * 4);
        else if (c4 < 12516)
            ezbuf = *reinterpret_cast<const float4*>(&ez[(size_t)b * NOOV_ + (c4 - 12500) * 4]);
    }
    __syncthreads();
#pragma unroll
    for (int k = 0; k < 13; ++k) {
        int c4 = tid + (k << 10);
        if (c4 < 12500) {
            uint2 e = buf[k];
            float4 v;
            v.x = __uint_as_float((e.x & 0xffffu) << 16) * s;
            v.y = __uint_as_float(e.x & 0xffff0000u) * s;
            v.z = __uint_as_float((e.y & 0xffffu) << 16) * s;
            v.w = __uint_as_float(e.y & 0xffff0000u) * s;
            *reinterpret_cast<float4*>(row + c4 * 4) = v;
        } else if (c4 < 12516) {
            *reinterpret_cast<float4*>(row + c4 * 4) = ezbuf;
        }
    }
}

// ---------------------------------------------------------------------------
// coverage copy + scatter-add pointer distribution. 512 blocks x 512 thr.
// ---------------------------------------------------------------------------
__global__ __launch_bounds__(512) void scatter_cov(float* __restrict__ outF,
                                                   const float* __restrict__ adw,
                                                   const float* __restrict__ attn,
                                                   const int* __restrict__ ebev,
                                                   const float* __restrict__ cov,
                                                   float* __restrict__ outCov) {
    const int b = blockIdx.x;
    const int tid = threadIdx.x;
    if (tid < 128)
        reinterpret_cast<float4*>(outCov + (size_t)b * 512)[tid] =
            reinterpret_cast<const float4*>(cov + (size_t)b * 512)[tid];
    float ad = adw[b];
    int col = ebev[(size_t)b * 512 + tid];
    float val = ad * attn[(size_t)b * 512 + tid];
    atomicAdd(&outF[(size_t)b * VE_ + col], val);
}

// ---------------------------------------------------------------------------
extern "C" void kernel_launch(void* const* d_in, const int* in_sizes, int n_in,
                              void* d_out, int out_size, void* d_ws, size_t ws_size,
                              hipStream_t stream) {
    const int*   y    = (const int*)d_in[0];
    const float* h0   = (const float*)d_in[1];
    const float* c0   = (const float*)d_in[2];
    const float* ct1  = (const float*)d_in[3];
    const float* ez   = (const float*)d_in[4];
    const int*   ebev = (const int*)d_in[5];
    const float* cov  = (const float*)d_in[6];
    const float* emb  = (const float*)d_in[7];
    const float* Wx   = (const float*)d_in[8];
    const float* bx   = (const float*)d_in[9];
    const float* Wih  = (const float*)d_in[10];
    const float* Whh  = (const float*)d_in[11];
    const float* bih  = (const float*)d_in[12];
    const float* bhh  = (const float*)d_in[13];
    const float* memp = (const float*)d_in[14];
    const float* Wdp  = (const float*)d_in[15];
    const float* bdp  = (const float*)d_in[16];
    const float* vw   = (const float*)d_in[17];
    const float* Wpg  = (const float*)d_in[18];
    const float* bpg  = (const float*)d_in[19];
    const float* Wo1  = (const float*)d_in[20];
    const float* bo1  = (const float*)d_in[21];
    const float* Wo2  = (const float*)d_in[22];
    const float* bo2  = (const float*)d_in[23];

    float* out = (float*)d_out;
    const size_t OUT_FINAL = 0;
    const size_t OUT_H    = (size_t)B_ * VE_;
    const size_t OUT_C    = OUT_H + (size_t)B_ * H_;
    const size_t OUT_CT   = OUT_C + (size_t)B_ * H_;
    const size_t OUT_ATTN = OUT_CT + (size_t)B_ * 2 * H_;
    const size_t OUT_PG   = OUT_ATTN + (size_t)B_ * TK_;
    const size_t OUT_COV  = OUT_PG + B_;

    // ---- workspace layout ----
    char* wb = (char*)d_ws;
    float* xw     = (float*)wb;                       // 131072
    float* gates  = xw + 131072;                      // 524288
    float* scat   = gates + 524288;                   // 262144
    float* dec    = scat + 262144;                    // 262144
    float* scores = dec + 262144;                     // 262144
    float* ps     = scores + 262144;                  // 400384
    float* bsum   = ps + 400384;                      // 1024
    float* pgw    = bsum + 1024;                      // 512
    float* scalew = pgw + 512;                        // 512
    float* adw    = scalew + 512;                     // 512
    unsigned short* Wx_bf   = (unsigned short*)(adw + 512);
    unsigned short* Wcat_bf = Wx_bf + 196608;
    unsigned short* Wdp_bf  = Wcat_bf + 524288;
    unsigned short* Wo1_bf  = Wdp_bf + 262144;
    unsigned short* xcat_bf = Wo1_bf + 196608;
    unsigned short* xh_bf   = xcat_bf + 393216;
    unsigned short* scat_bf = xh_bf + 262144;
    unsigned short* hc_bf   = scat_bf + 262144;
    unsigned short* out1_bf = hc_bf + 393216;

    // 0) conversions / gathers
    prep_small<<<(PR_END + 255) / 256, 256, 0, stream>>>(
        Wx, Wdp, Wo1, Wih, Whh, bih, bhh, y, ct1, emb, h0,
        Wx_bf, Wdp_bf, Wo1_bf, Wcat_bf, xcat_bf, xh_bf, bsum);

    // 1) x = cat(c_t_1, emb[y]) @ Wx^T + bx  -> f32 xw + bf16 into xh_bf[:,0:256]
    gemm64<<<dim3(4, 8), 256, 0, stream>>>(xcat_bf, Wx_bf, bx, xw, xh_bf,
                                           256, 768, 512, 0, 0);

    // 2) LSTM gates + pointwise
    gemm64<<<dim3(16, 8), 256, 0, stream>>>(xh_bf, Wcat_bf, bsum, gates, nullptr,
                                            1024, 512, 0, 0, 0);
    lstm_pw<<<512, 256, 0, stream>>>(gates, c0, out + OUT_H, out + OUT_C,
                                     scat, scat_bf, hc_bf);

    // 3) attention
    gemm64<<<dim3(8, 8), 256, 0, stream>>>(scat_bf, Wdp_bf, bdp, dec, nullptr,
                                           512, 512, 0, 0, 0);
    attn_scores<<<dim3(32, 32), 256, 0, stream>>>(memp, dec, vw, scores);
    softmax_k<<<64, 256, 0, stream>>>(scores, out + OUT_ATTN);
    ct_k<<<dim3(4, 64), 256, 0, stream>>>(out + OUT_ATTN, memp, out + OUT_CT, hc_bf);

    // 4) p_gen
    pgen_k<<<512, 256, 0, stream>>>(out + OUT_CT, scat, xw, Wpg, bpg,
                                    out + OUT_PG, pgw);

    // 5) vocab distribution: out1 -> exp-stash + partial sums -> scaled write
    gemm64<<<dim3(4, 8), 256, 0, stream>>>(hc_bf, Wo1_bf, bo1, nullptr, out1_bf,
                                           256, 768, 256, 0, 1);
    gemm_sum<<<dim3(4, NCB_), 512, 0, stream>>>(out1_bf, Wo2, bo2,
                                                out + OUT_FINAL, ps);
    rowsum_k<<<512, 64, 0, stream>>>(ps, pgw, scalew, adw);
    final_write<<<512, 1024, 0, stream>>>(out + OUT_FINAL, scalew, ez);

    // 6) coverage + scatter-add
    scatter_cov<<<512, 512, 0, stream>>>(out + OUT_FINAL, adw, out + OUT_ATTN,
                                         ebev, cov, out + OUT_COV);
}

// Round 4
// 252.323 us; speedup vs baseline: 1.9400x; 1.0591x over previous
//
#include <hip/hip_runtime.h>
#include <hip/hip_bf16.h>

// Problem constants
#define B_  512
#define H_  256
#define TK_ 512
#define V_  50000
#define NOOV_ 64
#define VE_ (V_ + NOOV_)   // 50064
#define NCB_ 391           // ceil(50000/128)
#define ELOFF 25032        // float offset of bf16 exp-stash inside each out row

typedef __bf16 bf16_t;
typedef __bf16 bf16x8 __attribute__((ext_vector_type(8)));
typedef float  f32x4  __attribute__((ext_vector_type(4)));

#define DEVI __device__ __forceinline__

DEVI float fast_rcp(float x) { return __builtin_amdgcn_rcpf(x); }
DEVI float fast_tanh(float x) {
    float e = __expf(2.f * x);
    return 1.f - 2.f * fast_rcp(e + 1.f);
}
DEVI float fast_sig(float x) { return fast_rcp(1.f + __expf(-x)); }

DEVI unsigned f2bf1(float f) {
    unsigned u = __float_as_uint(f);
    return (u + 0x7fffu + ((u >> 16) & 1u)) >> 16;   // RNE
}
DEVI unsigned f2bf2(float lo, float hi) { return f2bf1(lo) | (f2bf1(hi) << 16); }

DEVI uint4 cvt8(const float* p) {
    float4 a = *reinterpret_cast<const float4*>(p);
    float4 b = *reinterpret_cast<const float4*>(p + 4);
    uint4 r;
    r.x = f2bf2(a.x, a.y); r.y = f2bf2(a.z, a.w);
    r.z = f2bf2(b.x, b.y); r.w = f2bf2(b.z, b.w);
    return r;
}

// ---------------------------------------------------------------------------
// All small conversions / gathers in one kernel (uint4-granular items)
// ---------------------------------------------------------------------------
#define PR_O1 24576    // Wx end
#define PR_O2 57344    // Wdp end
#define PR_O3 81920    // Wo1 end
#define PR_O4 147456   // Wcat end
#define PR_O5 196608   // xcat end
#define PR_O6 212992   // xh-h0 end
#define PR_END 213120  // bsum end

__global__ __launch_bounds__(256) void prep_small(
        const float* __restrict__ Wx, const float* __restrict__ Wdp,
        const float* __restrict__ Wo1,
        const float* __restrict__ Wih, const float* __restrict__ Whh,
        const float* __restrict__ bih, const float* __restrict__ bhh,
        const int* __restrict__ y, const float* __restrict__ ct1,
        const float* __restrict__ emb, const float* __restrict__ h0,
        unsigned short* __restrict__ Wx_bf, unsigned short* __restrict__ Wdp_bf,
        unsigned short* __restrict__ Wo1_bf, unsigned short* __restrict__ Wcat_bf,
        unsigned short* __restrict__ xcat_bf, unsigned short* __restrict__ xh_bf,
        float* __restrict__ bsum) {
    int idx = blockIdx.x * 256 + threadIdx.x;
    if (idx >= PR_END) return;
    if (idx < PR_O1) {
        reinterpret_cast<uint4*>(Wx_bf)[idx] = cvt8(Wx + (size_t)idx * 8);
    } else if (idx < PR_O2) {
        int i = idx - PR_O1;
        reinterpret_cast<uint4*>(Wdp_bf)[i] = cvt8(Wdp + (size_t)i * 8);
    } else if (idx < PR_O3) {
        int i = idx - PR_O2;
        reinterpret_cast<uint4*>(Wo1_bf)[i] = cvt8(Wo1 + (size_t)i * 8);
    } else if (idx < PR_O4) {
        int i = idx - PR_O3;
        int r = i >> 6, c = (i & 63) * 8;
        const float* src = (c < 256) ? &Wih[(size_t)r * 256 + c]
                                     : &Whh[(size_t)r * 256 + (c - 256)];
        *reinterpret_cast<uint4*>(&Wcat_bf[(size_t)r * 512 + c]) = cvt8(src);
    } else if (idx < PR_O5) {
        int i = idx - PR_O4;
        int b = i / 96, j = (i - b * 96) * 8;
        const float* src = (j < 512) ? &ct1[(size_t)b * 512 + j]
                                     : &emb[(size_t)y[b] * 256 + (j - 512)];
        *reinterpret_cast<uint4*>(&xcat_bf[(size_t)b * 768 + j]) = cvt8(src);
    } else if (idx < PR_O6) {
        int i = idx - PR_O5;
        int b = i >> 5, c = (i & 31) * 8;
        *reinterpret_cast<uint4*>(&xh_bf[(size_t)b * 512 + 256 + c]) =
            cvt8(&h0[(size_t)b * 256 + c]);
    } else {
        int g0 = (idx - PR_O6) * 8;
#pragma unroll
        for (int k = 0; k < 8; ++k) bsum[g0 + k] = bih[g0 + k] + bhh[g0 + k];
    }
}

// ---------------------------------------------------------------------------
// Small GEMM: C[M,N] = A[M,K](bf16) * B[N,K]^T(bf16) + bias
// BM=BN=64, BK=64, 256 threads (4 waves 2x2, each 32x32 = 2x2 frags)
// ---------------------------------------------------------------------------
__global__ __launch_bounds__(256) void gemm64(const unsigned short* __restrict__ Abf,
                                              const unsigned short* __restrict__ Bbf,
                                              const float* __restrict__ bias,
                                              float* __restrict__ Cf,
                                              unsigned short* __restrict__ Cb,
                                              int N, int K, int ldcb, int ocb,
                                              int relu) {
    __shared__ unsigned short As[64][72];
    __shared__ unsigned short Bs[64][72];
    const int tid = threadIdx.x;
    const int m0 = blockIdx.y * 64;
    const int n0 = blockIdx.x * 64;
    const int lane = tid & 63;
    const int wid = tid >> 6;
    const int wm = wid >> 1, wn = wid & 1;

    f32x4 acc[2][2] = {};

    for (int k0 = 0; k0 < K; k0 += 64) {
#pragma unroll
        for (int i = 0; i < 2; ++i) {
            int idx = tid + i * 256;       // 512 uint4 slots
            int r = idx >> 3;
            int c = (idx & 7) * 8;
            *reinterpret_cast<uint4*>(&As[r][c]) =
                *reinterpret_cast<const uint4*>(&Abf[(size_t)(m0 + r) * K + k0 + c]);
            *reinterpret_cast<uint4*>(&Bs[r][c]) =
                *reinterpret_cast<const uint4*>(&Bbf[(size_t)(n0 + r) * K + k0 + c]);
        }
        __syncthreads();
#pragma unroll
        for (int ks = 0; ks < 64; ks += 32) {
            int koff = ks + (lane >> 4) * 8;
            bf16x8 af[2], bfv[2];
#pragma unroll
            for (int mi = 0; mi < 2; ++mi)
                af[mi] = *reinterpret_cast<const bf16x8*>(&As[wm * 32 + mi * 16 + (lane & 15)][koff]);
#pragma unroll
            for (int ni = 0; ni < 2; ++ni)
                bfv[ni] = *reinterpret_cast<const bf16x8*>(&Bs[wn * 32 + ni * 16 + (lane & 15)][koff]);
#pragma unroll
            for (int mi = 0; mi < 2; ++mi)
#pragma unroll
                for (int ni = 0; ni < 2; ++ni)
                    acc[mi][ni] = __builtin_amdgcn_mfma_f32_16x16x32_bf16(af[mi], bfv[ni], acc[mi][ni], 0, 0, 0);
        }
        __syncthreads();
    }

#pragma unroll
    for (int mi = 0; mi < 2; ++mi)
#pragma unroll
        for (int ni = 0; ni < 2; ++ni) {
            int c = n0 + wn * 32 + ni * 16 + (lane & 15);
            float bv = bias[c];
#pragma unroll
            for (int r = 0; r < 4; ++r) {
                int rr = m0 + wm * 32 + mi * 16 + (lane >> 4) * 4 + r;
                float v = acc[mi][ni][r] + bv;
                if (relu) v = fmaxf(v, 0.f);
                if (Cf) Cf[(size_t)rr * N + c] = v;
                if (Cb) Cb[(size_t)rr * ldcb + ocb + c] = (unsigned short)f2bf1(v);
            }
        }
}

// ---------------------------------------------------------------------------
// Vocab GEMM: logits = out1[512,256](bf16) @ Wo2[50000,256]^T(f32 inline-cvt)
// + bo2; writes bf16 exp(logit) stash + per-(cb,row,half) partial sums.
// 512 threads = 8 waves (4x2), BM=BN=128, BK=64 (36.9KB LDS -> 4 blocks/CU).
// 1D grid 1564, XCD-swizzled so the 4 m-blocks of a cb share an XCD L2.
// ---------------------------------------------------------------------------
__global__ __launch_bounds__(512) void gemm_sum(const unsigned short* __restrict__ Abf,
                                                const float* __restrict__ Wo2,
                                                const float* __restrict__ bo2,
                                                float* __restrict__ outF,
                                                float* __restrict__ ps) {
    __shared__ unsigned short As[128][72];
    __shared__ unsigned short Bs[128][72];
    const int f = blockIdx.x;
    int cb, mB;
    if (f < 1536) { cb = (f >> 5) * 8 + (f & 7); mB = (f >> 3) & 3; }
    else { int t = f - 1536; cb = 384 + t % 7; mB = t / 7; }
    const int tid = threadIdx.x;
    const int m0 = mB * 128;
    const int n0 = cb * 128;
    const int lane = tid & 63;
    const int wid = tid >> 6;
    const int wm = wid >> 1, wn = wid & 1;   // 4 x 2

    f32x4 acc[2][4] = {};

    for (int k0 = 0; k0 < 256; k0 += 64) {
#pragma unroll
        for (int i = 0; i < 2; ++i) {
            int idx = tid + i * 512;       // 1024 uint4 slots per matrix
            int r = idx >> 3;
            int c = (idx & 7) * 8;
            *reinterpret_cast<uint4*>(&As[r][c]) =
                *reinterpret_cast<const uint4*>(&Abf[(size_t)(m0 + r) * 256 + k0 + c]);
            uint4 vb = make_uint4(0u, 0u, 0u, 0u);
            if (n0 + r < V_)
                vb = cvt8(&Wo2[(size_t)(n0 + r) * 256 + k0 + c]);
            *reinterpret_cast<uint4*>(&Bs[r][c]) = vb;
        }
        __syncthreads();
#pragma unroll
        for (int ks = 0; ks < 64; ks += 32) {
            int koff = ks + (lane >> 4) * 8;
            bf16x8 af[2], bfv[4];
#pragma unroll
            for (int mi = 0; mi < 2; ++mi)
                af[mi] = *reinterpret_cast<const bf16x8*>(&As[wm * 32 + mi * 16 + (lane & 15)][koff]);
#pragma unroll
            for (int ni = 0; ni < 4; ++ni)
                bfv[ni] = *reinterpret_cast<const bf16x8*>(&Bs[wn * 64 + ni * 16 + (lane & 15)][koff]);
#pragma unroll
            for (int mi = 0; mi < 2; ++mi)
#pragma unroll
                for (int ni = 0; ni < 4; ++ni)
                    acc[mi][ni] = __builtin_amdgcn_mfma_f32_16x16x32_bf16(af[mi], bfv[ni], acc[mi][ni], 0, 0, 0);
        }
        __syncthreads();
    }

    float psum[2][4];
#pragma unroll
    for (int mi = 0; mi < 2; ++mi)
#pragma unroll
        for (int r = 0; r < 4; ++r) psum[mi][r] = 0.f;

#pragma unroll
    for (int mi = 0; mi < 2; ++mi)
#pragma unroll
        for (int ni = 0; ni < 4; ++ni) {
            int c = n0 + wn * 64 + ni * 16 + (lane & 15);
            bool ok = (c < V_);
            float bv = ok ? bo2[c] : 0.f;
#pragma unroll
            for (int r = 0; r < 4; ++r) {
                int rr = m0 + wm * 32 + mi * 16 + (lane >> 4) * 4 + r;
                float p = __expf(acc[mi][ni][r] + bv);
                unsigned eb = f2bf1(p);
                if (ok) {
                    unsigned short* el =
                        (unsigned short*)(outF + (size_t)rr * VE_ + ELOFF);
                    el[c] = (unsigned short)eb;
                    psum[mi][r] += __uint_as_float(eb << 16);
                }
            }
        }

#pragma unroll
    for (int mi = 0; mi < 2; ++mi)
#pragma unroll
        for (int r = 0; r < 4; ++r) {
            float v = psum[mi][r];
            v += __shfl_xor(v, 1);
            v += __shfl_xor(v, 2);
            v += __shfl_xor(v, 4);
            v += __shfl_xor(v, 8);
            if ((lane & 15) == 0) {
                int rr = m0 + wm * 32 + mi * 16 + (lane >> 4) * 4 + r;
                ps[((size_t)cb * 512 + rr) * 2 + wn] = v;
            }
        }
}

// ---------------------------------------------------------------------------
// scores[b,t] = sum_d tanh(mem[t,d] + dec[b,d]) * vw[d]   (d=512)
// ---------------------------------------------------------------------------
__global__ __launch_bounds__(256) void attn_scores(const float* __restrict__ mem,
                                                   const float* __restrict__ dec,
                                                   const float* __restrict__ vw,
                                                   float* __restrict__ scores) {
    __shared__ float ms[16][132];
    __shared__ float dsh[16][132];
    __shared__ float vs[128];
    const int tid = threadIdx.x;
    const int t0 = blockIdx.x * 16, b0 = blockIdx.y * 16;
    const int tl = tid & 15, bl = tid >> 4;
    float acc = 0.f;
    for (int d0 = 0; d0 < 512; d0 += 128) {
#pragma unroll
        for (int u = 0; u < 2; ++u) {
            int fi = tid + u * 256;
            int r = fi >> 5, c4 = fi & 31;
            *reinterpret_cast<float4*>(&ms[r][c4 * 4]) =
                *reinterpret_cast<const float4*>(&mem[(size_t)(t0 + r) * 512 + d0 + c4 * 4]);
            *reinterpret_cast<float4*>(&dsh[r][c4 * 4]) =
                *reinterpret_cast<const float4*>(&dec[(size_t)(b0 + r) * 512 + d0 + c4 * 4]);
        }
        if (tid < 32)
            *reinterpret_cast<float4*>(&vs[tid * 4]) =
                *reinterpret_cast<const float4*>(&vw[d0 + tid * 4]);
        __syncthreads();
#pragma unroll 8
        for (int j = 0; j < 128; j += 4) {
            float4 mv = *reinterpret_cast<const float4*>(&ms[tl][j]);
            float4 dv = *reinterpret_cast<const float4*>(&dsh[bl][j]);
            float4 wv = *reinterpret_cast<const float4*>(&vs[j]);
            acc += wv.x * fast_tanh(mv.x + dv.x);
            acc += wv.y * fast_tanh(mv.y + dv.y);
            acc += wv.z * fast_tanh(mv.z + dv.z);
            acc += wv.w * fast_tanh(mv.w + dv.w);
        }
        __syncthreads();
    }
    scores[(size_t)(b0 + bl) * 512 + (t0 + tl)] = acc;
}

// ---------------------------------------------------------------------------
// softmax over TK per row (8 rows/block, 64 blocks) -> attn_out (f32)
// ---------------------------------------------------------------------------
__global__ __launch_bounds__(256) void softmax_k(const float* __restrict__ scores,
                                                 float* __restrict__ attn_out) {
    __shared__ float sl[8][512];
    const int tid = threadIdx.x;
    const int b0 = blockIdx.x * 8;
#pragma unroll
    for (int i = 0; i < 16; ++i) {
        int idx = tid + i * 256;
        int r = idx >> 9, c = idx & 511;
        sl[r][c] = scores[(size_t)(b0 + r) * 512 + c];
    }
    __syncthreads();
    int r = tid >> 5, li = tid & 31;
    float mx = -1e30f;
#pragma unroll
    for (int k = 0; k < 16; ++k) mx = fmaxf(mx, sl[r][li + k * 32]);
#pragma unroll
    for (int m = 1; m < 32; m <<= 1) mx = fmaxf(mx, __shfl_xor(mx, m));
    float pv[16];
    float sum = 0.f;
#pragma unroll
    for (int k = 0; k < 16; ++k) {
        float p = __expf(sl[r][li + k * 32] - mx);
        pv[k] = p;
        sum += p;
    }
#pragma unroll
    for (int m = 1; m < 32; m <<= 1) sum += __shfl_xor(sum, m);
    float inv = 1.f / sum;
#pragma unroll
    for (int k = 0; k < 16; ++k)
        attn_out[(size_t)(b0 + r) * 512 + li + k * 32] = pv[k] * inv;
}

// ---------------------------------------------------------------------------
// c_t = attn @ mem.  grid (4 d-chunks, 64 b-chunks), 256 thr: 128 cols x 8 rows
// ---------------------------------------------------------------------------
__global__ __launch_bounds__(256) void ct_k(const float* __restrict__ attn,
                                            const float* __restrict__ mem,
                                            float* __restrict__ ct_out,
                                            unsigned short* __restrict__ hc_bf) {
    __shared__ float al[8][512];
    const int tid = threadIdx.x;
    const int d0 = blockIdx.x * 128;
    const int b0 = blockIdx.y * 8;
#pragma unroll
    for (int i = 0; i < 16; ++i) {
        int idx = tid + i * 256;
        int r = idx >> 9, c = idx & 511;
        al[r][c] = attn[(size_t)(b0 + r) * 512 + c];
    }
    __syncthreads();
    const int c = tid & 127;
    const int h = tid >> 7;            // 0/1 -> rows b0+h*4 .. b0+h*4+3
    float acc[4] = {0.f, 0.f, 0.f, 0.f};
    for (int t = 0; t < 512; t += 2) {
        float m0v = mem[(size_t)t * 512 + d0 + c];
        float m1v = mem[(size_t)(t + 1) * 512 + d0 + c];
#pragma unroll
        for (int r = 0; r < 4; ++r) {
            acc[r] += al[h * 4 + r][t] * m0v;
            acc[r] += al[h * 4 + r][t + 1] * m1v;
        }
    }
#pragma unroll
    for (int r = 0; r < 4; ++r) {
        int b = b0 + h * 4 + r;
        ct_out[(size_t)b * 512 + d0 + c] = acc[r];
        hc_bf[(size_t)b * 768 + 256 + d0 + c] = (unsigned short)f2bf1(acc[r]);
    }
}

// ---------------------------------------------------------------------------
__global__ void lstm_pw(const float* __restrict__ gates, const float* __restrict__ c0,
                        float* __restrict__ outH, float* __restrict__ outC,
                        float* __restrict__ scat, unsigned short* __restrict__ scat_bf,
                        unsigned short* __restrict__ hc_bf) {
    int idx = blockIdx.x * 256 + threadIdx.x;   // 512*256
    int b = idx >> 8, j = idx & 255;
    const float* g = gates + (size_t)b * 1024;
    float ig = fast_sig(g[j]);
    float fg = fast_sig(g[256 + j]);
    float gg = fast_tanh(g[512 + j]);
    float og = fast_sig(g[768 + j]);
    float c = fg * c0[idx] + ig * gg;
    float h = og * fast_tanh(c);
    outH[idx] = h;
    outC[idx] = c;
    scat[(size_t)b * 512 + j] = h;
    scat[(size_t)b * 512 + 256 + j] = c;
    unsigned short hb = (unsigned short)f2bf1(h);
    unsigned short cb = (unsigned short)f2bf1(c);
    scat_bf[(size_t)b * 512 + j] = hb;
    scat_bf[(size_t)b * 512 + 256 + j] = cb;
    hc_bf[(size_t)b * 768 + j] = hb;
}

__global__ __launch_bounds__(256) void pgen_k(const float* __restrict__ ct,
                                              const float* __restrict__ scat,
                                              const float* __restrict__ x,
                                              const float* __restrict__ Wpg,
                                              const float* __restrict__ bpg,
                                              float* __restrict__ outPG,
                                              float* __restrict__ pgw) {
    int b = blockIdx.x, tid = threadIdx.x;
    float part = 0.f;
    for (int idx = tid; idx < 1280; idx += 256) {
        float wv = Wpg[idx];
        float xv;
        if (idx < 512) xv = ct[(size_t)b * 512 + idx];
        else if (idx < 1024) xv = scat[(size_t)b * 512 + idx - 512];
        else xv = x[(size_t)b * 256 + idx - 1024];
        part += wv * xv;
    }
    __shared__ float red[256];
    red[tid] = part;
    __syncthreads();
    for (int s = 128; s > 0; s >>= 1) {
        if (tid < s) red[tid] += red[tid + s];
        __syncthreads();
    }
    if (tid == 0) {
        float pgv = fast_sig(red[0] + bpg[0]);
        outPG[b] = pgv;
        pgw[b] = pgv;
    }
}

// per-row: scale = pgen/sum over all colblocks; adw = 1-pgen.  512 blocks x 64
__global__ __launch_bounds__(64) void rowsum_k(const float* __restrict__ ps,
                                               const float* __restrict__ pgw,
                                               float* __restrict__ scalew,
                                               float* __restrict__ adw) {
    int b = blockIdx.x;
    int lane = threadIdx.x;
    float s = 0.f;
    for (int cb = lane; cb < NCB_; cb += 64) {
        size_t o = ((size_t)cb * 512 + b) * 2;
        s += ps[o] + ps[o + 1];
    }
#pragma unroll
    for (int m = 1; m < 64; m <<= 1) s += __shfl_xor(s, m);
    if (lane == 0) {
        float pgv = pgw[b];
        scalew[b] = pgv / s;
        adw[b] = 1.f - pgv;
    }
}

// ---------------------------------------------------------------------------
// Finish: read bf16 exp-stash -> write scaled f32 row + extra_zeros, copy
// coverage, then scatter-add pointer distribution into the same row.
// One block per row, 1024 threads (in-place safe; atomics ordered by barrier).
// ---------------------------------------------------------------------------
__global__ __launch_bounds__(1024) void finish_k(float* __restrict__ outF,
                                                 const float* __restrict__ scalew,
                                                 const float* __restrict__ adw,
                                                 const float* __restrict__ ez,
                                                 const float* __restrict__ attn,
                                                 const int* __restrict__ ebev,
                                                 const float* __restrict__ cov,
                                                 float* __restrict__ outCov) {
    const int b = blockIdx.x;
    const int tid = threadIdx.x;
    const float s = scalew[b];
    float* row = outF + (size_t)b * VE_;
    const unsigned short* el = (const unsigned short*)(row + ELOFF);

    uint2 buf[13];
    float4 ezbuf;
#pragma unroll
    for (int k = 0; k < 13; ++k) {
        int c4 = tid + (k << 10);
        if (c4 < 12500)
            buf[k] = *reinterpret_cast<const uint2*>(el + c4 * 4);
        else if (c4 < 12516)
            ezbuf = *reinterpret_cast<const float4*>(&ez[(size_t)b * NOOV_ + (c4 - 12500) * 4]);
    }
    __syncthreads();
#pragma unroll
    for (int k = 0; k < 13; ++k) {
        int c4 = tid + (k << 10);
        if (c4 < 12500) {
            uint2 e = buf[k];
            float4 v;
            v.x = __uint_as_float((e.x & 0xffffu) << 16) * s;
            v.y = __uint_as_float(e.x & 0xffff0000u) * s;
            v.z = __uint_as_float((e.y & 0xffffu) << 16) * s;
            v.w = __uint_as_float(e.y & 0xffff0000u) * s;
            *reinterpret_cast<float4*>(row + c4 * 4) = v;
        } else if (c4 < 12516) {
            *reinterpret_cast<float4*>(row + c4 * 4) = ezbuf;
        }
    }
    if (tid < 128)
        reinterpret_cast<float4*>(outCov + (size_t)b * 512)[tid] =
            reinterpret_cast<const float4*>(cov + (size_t)b * 512)[tid];
    __syncthreads();
    if (tid < 512) {
        float ad = adw[b];
        int col = ebev[(size_t)b * 512 + tid];
        float val = ad * attn[(size_t)b * 512 + tid];
        atomicAdd(&row[col], val);
    }
}

// ---------------------------------------------------------------------------
extern "C" void kernel_launch(void* const* d_in, const int* in_sizes, int n_in,
                              void* d_out, int out_size, void* d_ws, size_t ws_size,
                              hipStream_t stream) {
    const int*   y    = (const int*)d_in[0];
    const float* h0   = (const float*)d_in[1];
    const float* c0   = (const float*)d_in[2];
    const float* ct1  = (const float*)d_in[3];
    const float* ez   = (const float*)d_in[4];
    const int*   ebev = (const int*)d_in[5];
    const float* cov  = (const float*)d_in[6];
    const float* emb  = (const float*)d_in[7];
    const float* Wx   = (const float*)d_in[8];
    const float* bx   = (const float*)d_in[9];
    const float* Wih  = (const float*)d_in[10];
    const float* Whh  = (const float*)d_in[11];
    const float* bih  = (const float*)d_in[12];
    const float* bhh  = (const float*)d_in[13];
    const float* memp = (const float*)d_in[14];
    const float* Wdp  = (const float*)d_in[15];
    const float* bdp  = (const float*)d_in[16];
    const float* vw   = (const float*)d_in[17];
    const float* Wpg  = (const float*)d_in[18];
    const float* bpg  = (const float*)d_in[19];
    const float* Wo1  = (const float*)d_in[20];
    const float* bo1  = (const float*)d_in[21];
    const float* Wo2  = (const float*)d_in[22];
    const float* bo2  = (const float*)d_in[23];

    float* out = (float*)d_out;
    const size_t OUT_FINAL = 0;
    const size_t OUT_H    = (size_t)B_ * VE_;
    const size_t OUT_C    = OUT_H + (size_t)B_ * H_;
    const size_t OUT_CT   = OUT_C + (size_t)B_ * H_;
    const size_t OUT_ATTN = OUT_CT + (size_t)B_ * 2 * H_;
    const size_t OUT_PG   = OUT_ATTN + (size_t)B_ * TK_;
    const size_t OUT_COV  = OUT_PG + B_;

    // ---- workspace layout ----
    char* wb = (char*)d_ws;
    float* xw     = (float*)wb;                       // 131072
    float* gates  = xw + 131072;                      // 524288
    float* scat   = gates + 524288;                   // 262144
    float* dec    = scat + 262144;                    // 262144
    float* scores = dec + 262144;                     // 262144
    float* ps     = scores + 262144;                  // 400384
    float* bsum   = ps + 400384;                      // 1024
    float* pgw    = bsum + 1024;                      // 512
    float* scalew = pgw + 512;                        // 512
    float* adw    = scalew + 512;                     // 512
    unsigned short* Wx_bf   = (unsigned short*)(adw + 512);
    unsigned short* Wcat_bf = Wx_bf + 196608;
    unsigned short* Wdp_bf  = Wcat_bf + 524288;
    unsigned short* Wo1_bf  = Wdp_bf + 262144;
    unsigned short* xcat_bf = Wo1_bf + 196608;
    unsigned short* xh_bf   = xcat_bf + 393216;
    unsigned short* scat_bf = xh_bf + 262144;
    unsigned short* hc_bf   = scat_bf + 262144;
    unsigned short* out1_bf = hc_bf + 393216;

    // 0) conversions / gathers
    prep_small<<<(PR_END + 255) / 256, 256, 0, stream>>>(
        Wx, Wdp, Wo1, Wih, Whh, bih, bhh, y, ct1, emb, h0,
        Wx_bf, Wdp_bf, Wo1_bf, Wcat_bf, xcat_bf, xh_bf, bsum);

    // 1) x = cat(c_t_1, emb[y]) @ Wx^T + bx  -> f32 xw + bf16 into xh_bf[:,0:256]
    gemm64<<<dim3(4, 8), 256, 0, stream>>>(xcat_bf, Wx_bf, bx, xw, xh_bf,
                                           256, 768, 512, 0, 0);

    // 2) LSTM gates + pointwise
    gemm64<<<dim3(16, 8), 256, 0, stream>>>(xh_bf, Wcat_bf, bsum, gates, nullptr,
                                            1024, 512, 0, 0, 0);
    lstm_pw<<<512, 256, 0, stream>>>(gates, c0, out + OUT_H, out + OUT_C,
                                     scat, scat_bf, hc_bf);

    // 3) attention
    gemm64<<<dim3(8, 8), 256, 0, stream>>>(scat_bf, Wdp_bf, bdp, dec, nullptr,
                                           512, 512, 0, 0, 0);
    attn_scores<<<dim3(32, 32), 256, 0, stream>>>(memp, dec, vw, scores);
    softmax_k<<<64, 256, 0, stream>>>(scores, out + OUT_ATTN);
    ct_k<<<dim3(4, 64), 256, 0, stream>>>(out + OUT_ATTN, memp, out + OUT_CT, hc_bf);

    // 4) p_gen
    pgen_k<<<512, 256, 0, stream>>>(out + OUT_CT, scat, xw, Wpg, bpg,
                                    out + OUT_PG, pgw);

    // 5) vocab distribution: out1 -> exp-stash + partial sums -> scaled write
    gemm64<<<dim3(4, 8), 256, 0, stream>>>(hc_bf, Wo1_bf, bo1, nullptr, out1_bf,
                                           256, 768, 256, 0, 1);
    gemm_sum<<<1564, 512, 0, stream>>>(out1_bf, Wo2, bo2, out + OUT_FINAL, ps);
    rowsum_k<<<512, 64, 0, stream>>>(ps, pgw, scalew, adw);

    // 6) finish: scale + extra_zeros + coverage + scatter-add
    finish_k<<<512, 1024, 0, stream>>>(out + OUT_FINAL, scalew, adw, ez,
                                       out + OUT_ATTN, ebev, cov, out + OUT_COV);
}